// Round 11
// baseline (342.272 us; speedup 1.0000x reference)
//
#include <hip/hip_runtime.h>
#include <hip/hip_fp16.h>
#include <math.h>

#define D 64
#define NPB 64            // nodes per fine bucket
#define MAXFB 1568        // padded bucket-array size (supports N <= 100352)
#define CHUNK 4096        // edges per k_cfill block
#define CHUNK_H 16384     // edges per k_hist block
#define SCAP 2048         // max staged records per bucket in k_bsort
#define GTP 68            // LDS g-tile row stride (272B: 16B-aligned, 2-way banks)

typedef __attribute__((ext_vector_type(8))) _Float16 f16x8;
typedef __attribute__((ext_vector_type(4))) float f32x4;

static inline size_t align256(size_t x) { return (x + 255) & ~(size_t)255; }

// fine-bucket histogram: LDS hist per 16K-edge chunk, few global atomics
__global__ __launch_bounds__(1024) void k_hist(const int* __restrict__ to, int E, int NFB,
                                               unsigned* __restrict__ bcnt) {
    __shared__ unsigned h[MAXFB];
    int t = threadIdx.x;
    for (int i = t; i < MAXFB; i += 1024) h[i] = 0;
    __syncthreads();
    int base = blockIdx.x * CHUNK_H;
    int cnt = E - base; if (cnt > CHUNK_H) cnt = CHUNK_H;
    for (int j = t; j < cnt; j += 1024)
        atomicAdd(&h[((unsigned)to[base + j]) >> 6], 1u);
    __syncthreads();
    for (int i = t; i < NFB; i += 1024) {
        unsigned c = h[i];
        if (c) atomicAdd(&bcnt[i], c);
    }
}

// single-block scan of bcnt -> fine_base[NFB+1], gcur[NFB]
__global__ __launch_bounds__(1024) void k_scanb(const unsigned* __restrict__ bcnt, int NFB,
                                                int* __restrict__ fine_base, int* __restrict__ gcur) {
    __shared__ unsigned sh[1024];
    int t = threadIdx.x;
    int i0 = 2 * t, i1 = 2 * t + 1;
    unsigned a0 = (i0 < NFB) ? bcnt[i0] : 0u;
    unsigned a1 = (i1 < NFB) ? bcnt[i1] : 0u;
    unsigned sum = a0 + a1;
    sh[t] = sum;
    __syncthreads();
    for (int ofs = 1; ofs < 1024; ofs <<= 1) {
        unsigned v = (t >= ofs) ? sh[t - ofs] : 0u;
        __syncthreads();
        sh[t] += v;
        __syncthreads();
    }
    unsigned eb = sh[t] - sum;
    if (i0 < NFB) { fine_base[i0] = (int)eb; gcur[i0] = (int)eb; }
    if (i1 < NFB) { fine_base[i1] = (int)(eb + a0); gcur[i1] = (int)(eb + a0); }
    if (t == 0) fine_base[NFB] = (int)sh[1023];
}

// LDS-staged binned fill: records {frm | (to&63)<<20, w_raw} grouped by fine bucket.
__global__ __launch_bounds__(1024) void k_cfill(
        const int* __restrict__ frm, const int* __restrict__ to, const float* __restrict__ w,
        int E, int NFB, int* __restrict__ gcur, int2* __restrict__ ert) {
    __shared__ int2 stage[CHUNK];
    __shared__ unsigned short sfb[CHUNK];
    __shared__ unsigned hist[MAXFB];
    __shared__ unsigned scanE[MAXFB];
    __shared__ unsigned lbase[MAXFB];
    __shared__ unsigned sh[1024];
    int t = threadIdx.x;
    int base = blockIdx.x * CHUNK;
    int cnt = E - base; if (cnt > CHUNK) cnt = CHUNK;
    for (int b = t; b < MAXFB; b += 1024) hist[b] = 0;
    __syncthreads();
    int2 rec[4]; int fbv[4];
#pragma unroll
    for (int i = 0; i < 4; ++i) {
        int e = base + t + i * 1024;
        fbv[i] = -1;
        if (e < E) {
            int f = frm[e], tt = to[e];
            rec[i].x = f | ((tt & (NPB - 1)) << 20);
            rec[i].y = __float_as_int(w[e]);
            int fb = tt >> 6;
            fbv[i] = fb;
            atomicAdd(&hist[fb], 1u);
        }
    }
    __syncthreads();
    int i0 = 2 * t, i1 = 2 * t + 1;
    unsigned a0 = (i0 < MAXFB) ? hist[i0] : 0u;
    unsigned a1 = (i1 < MAXFB) ? hist[i1] : 0u;
    unsigned sum = a0 + a1;
    sh[t] = sum;
    __syncthreads();
    for (int ofs = 1; ofs < 1024; ofs <<= 1) {
        unsigned v = (t >= ofs) ? sh[t - ofs] : 0u;
        __syncthreads();
        sh[t] += v;
        __syncthreads();
    }
    unsigned eb = sh[t] - sum;
    if (i0 < MAXFB) scanE[i0] = eb;
    if (i1 < MAXFB) scanE[i1] = eb + a0;
    __syncthreads();
    for (int b = t; b < NFB; b += 1024) {
        unsigned c = hist[b];
        if (c) lbase[b] = (unsigned)atomicAdd(&gcur[b], (int)c);
        hist[b] = 0;
    }
    __syncthreads();
#pragma unroll
    for (int i = 0; i < 4; ++i) {
        if (fbv[i] >= 0) {
            unsigned loc = atomicAdd(&hist[fbv[i]], 1u);
            unsigned slot = scanE[fbv[i]] + loc;
            stage[slot] = rec[i];
            sfb[slot] = (unsigned short)fbv[i];
        }
    }
    __syncthreads();
    for (int j = t; j < cnt; j += 1024) {
        int fb = sfb[j];
        ert[(int)lbase[fb] + (j - (int)scanE[fb])] = stage[j];
    }
}

// per-bucket LDS counting sort. Per-node counts == deg -> computes dis here,
// applies dis[to] to the record, strips tl bits, writes rowptr + dis.
__global__ __launch_bounds__(256) void k_bsort(
        const int2* __restrict__ ert, const int* __restrict__ fine_base,
        int N, int NFB, int2* __restrict__ er, int* __restrict__ rowptr,
        float* __restrict__ dis) {
    __shared__ int2 st[SCAP];
    __shared__ int2 st2[SCAP];
    __shared__ unsigned cnt[NPB];
    __shared__ unsigned cbase[NPB];
    __shared__ float dl[NPB];
    int fb = blockIdx.x;
    int b0 = fine_base[fb], b1 = fine_base[fb + 1];
    int len = b1 - b0;
    int t = threadIdx.x;
    if (t < NPB) cnt[t] = 0;
    __syncthreads();
    if (len <= SCAP) {
        for (int j = t; j < len; j += 256) {
            int2 r = ert[b0 + j];
            st[j] = r;
            atomicAdd(&cnt[(r.x >> 20) & 63], 1u);
        }
        __syncthreads();
        if (t < NPB) { unsigned c = cnt[t]; dl[t] = c ? 1.0f / sqrtf((float)c) : 0.0f; }
        __syncthreads();
        if (t == 0) {
            unsigned run = 0;
            for (int i = 0; i < NPB; ++i) { cbase[i] = run; run += cnt[i]; cnt[i] = 0; }
        }
        __syncthreads();
        for (int j = t; j < len; j += 256) {
            int2 r = st[j];
            int n = (r.x >> 20) & 63;
            unsigned loc = atomicAdd(&cnt[n], 1u);
            int2 o;
            o.x = r.x & 0xFFFFF;
            o.y = __float_as_int(__int_as_float(r.y) * dl[n]);
            st2[cbase[n] + loc] = o;
        }
        __syncthreads();
        for (int j = t; j < len; j += 256) er[b0 + j] = st2[j];
    } else {
        for (int j = t; j < len; j += 256)
            atomicAdd(&cnt[(ert[b0 + j].x >> 20) & 63], 1u);
        __syncthreads();
        if (t < NPB) { unsigned c = cnt[t]; dl[t] = c ? 1.0f / sqrtf((float)c) : 0.0f; }
        __syncthreads();
        if (t == 0) {
            unsigned run = 0;
            for (int i = 0; i < NPB; ++i) { cbase[i] = run; run += cnt[i]; cnt[i] = 0; }
        }
        __syncthreads();
        for (int j = t; j < len; j += 256) {
            int2 r = ert[b0 + j];
            int n = (r.x >> 20) & 63;
            unsigned loc = atomicAdd(&cnt[n], 1u);
            int2 o;
            o.x = r.x & 0xFFFFF;
            o.y = __float_as_int(__int_as_float(r.y) * dl[n]);
            er[b0 + (int)cbase[n] + (int)loc] = o;
        }
        __syncthreads();
    }
    int nbase = fb * NPB;
    if (t < NPB && nbase + t < N) {
        rowptr[nbase + t] = b0 + (int)cbase[t];
        dis[nbase + t] = dl[t];
    }
    if (fb == NFB - 1 && t == 0) rowptr[N] = b1;
}

// weight fragment table: wf[layer][mat][nt][ks][lane] = 8 f16 (16B), L1-resident in k_flayer
__global__ void k_wprep(const float* __restrict__ W1, const float* __restrict__ W2,
                        int Lnum, f16x8* __restrict__ wf) {
    int idx = blockIdx.x * blockDim.x + threadIdx.x;   // (layer*16 + frag)*64 + lane
    if (idx >= Lnum * 16 * 64) return;
    int lane = idx & 63;
    int fr = (idx >> 6) & 15;
    int l = idx >> 10;
    int mat = fr >> 3, nt = (fr >> 1) & 3, ks = fr & 1;
    int j = nt * 16 + (lane & 15);
    int kb = ((lane >> 4) << 3) + ks * 32;
    const float* src = (mat ? W2 : W1) + (size_t)l * D * D + j * D + kb;
    f16x8 v;
#pragma unroll
    for (int q = 0; q < 8; ++q) v[q] = (_Float16)src[q];
    wf[idx] = v;
}

// fused setup streaming pass: er.y *= dis[frm]  AND  emb -> x(fp16), out0, out1-cols0..63
__global__ void k_prep(int2* __restrict__ er, const float* __restrict__ dis, int E,
                       const float* __restrict__ emb, __half* __restrict__ x,
                       float* __restrict__ out, int N) {
    int total = E + N * 16;
    int st = gridDim.x * blockDim.x;
    const float4* e4 = (const float4*)emb;
    float4* o4 = (float4*)out;
    __half2* xh = (__half2*)x;
    for (int i = blockIdx.x * blockDim.x + threadIdx.x; i < total; i += st) {
        if (i < E) {
            int2 r = er[i];
            er[i].y = __float_as_int(__int_as_float(r.y) * dis[r.x]);
        } else {
            int j = i - E;
            float4 v = e4[j];
            o4[j] = v;
            int n = j >> 4, c = j & 15;
            o4[(size_t)N * 16 + (size_t)n * 32 + c] = v;
            xh[2 * j]     = __floats2half2_rn(v.x, v.y);
            xh[2 * j + 1] = __floats2half2_rn(v.z, v.w);
        }
    }
}

// ---- dual-stream gather helpers ----
__device__ __forceinline__ void load8(const int2* __restrict__ er, int e,
                                      const char* __restrict__ xbase, unsigned laneoff,
                                      float* vb, float* nb) {
#pragma unroll
    for (int k = 0; k < 8; ++k) {
        int2 r = er[e + k];
        unsigned off = ((unsigned)r.x << 7) | laneoff;   // 32-bit byte offset, saddr form
        vb[k] = __half2float(*(const __half*)(xbase + off));
        nb[k] = __int_as_float(r.y);
    }
}

__device__ __forceinline__ void consume8(const float* vb, const float* nb,
                                         const int* __restrict__ rowptr,
                                         float* gtw, float* stw,
                                         int lane, int tb, int lim,
                                         int& e, int& n, int& nend,
                                         float& gacc, float& sv) {
#pragma unroll
    for (int k = 0; k < 8; ++k) {
        gacc = fmaf(nb[k], vb[k], gacc);
        sv += nb[k];
        if (e + k + 1 == nend) {                 // wave-uniform flush
            gtw[(n - tb) * GTP + lane] = gacc;
            if (lane == 0) stw[n - tb] = sv;
            gacc = 0.0f; sv = 0.0f;
            if (e + k + 1 < lim) {
                ++n; nend = rowptr[n + 1];
                while (nend <= e + k + 1) { ++n; nend = rowptr[n + 1]; }
            } else nend = 0x7fffffff;
        }
    }
    e += 8;
}

__device__ __forceinline__ void tailK(const int2* __restrict__ er,
                                      const char* __restrict__ xbase, unsigned laneoff,
                                      const int* __restrict__ rowptr,
                                      float* gtw, float* stw,
                                      int lane, int tb, int K, int lim,
                                      int& e, int& n, int& nend,
                                      float& gacc, float& sv) {
    for (int k = 0; k < K; ++k) {
        int2 r = er[e + k];
        unsigned off = ((unsigned)r.x << 7) | laneoff;
        float nv = __int_as_float(r.y);
        gacc = fmaf(nv, __half2float(*(const __half*)(xbase + off)), gacc);
        sv += nv;
        if (e + k + 1 == nend) {
            gtw[(n - tb) * GTP + lane] = gacc;
            if (lane == 0) stw[n - tb] = sv;
            gacc = 0.0f; sv = 0.0f;
            if (e + k + 1 < lim) {
                ++n; nend = rowptr[n + 1];
                while (nend <= e + k + 1) { ++n; nend = rowptr[n + 1]; }
            } else nend = 0x7fffffff;
        }
    }
    e += K;
}

// fused layer, dual-stream: wave owns 16 nodes split into two independent
// 8-node streams (A/B) with interleaved 8-deep load batches -> 2x memory
// concurrency per wave. Flush = 1 ds_write per node; MFMA epilogue from LDS.
__global__ __launch_bounds__(256) void k_flayer(
        const int* __restrict__ rowptr, const int2* __restrict__ er,
        const __half* __restrict__ xin, const f16x8* __restrict__ wfg,
        const float* __restrict__ b1, const float* __restrict__ b2,
        int N, float* __restrict__ outf, __half* __restrict__ outh, int ostride) {
    __shared__ __align__(16) float gt[4][16][GTP];      // 17.4 KB, wave-private tiles
    __shared__ float stl[4][16];
    int tid = threadIdx.x;
    int lane = tid & 63, wv = tid >> 6;
    int tb = (blockIdx.x * 4 + wv) * 16;
    if (tb >= N) return;
    float* gtw = &gt[wv][0][0];
    float* stw = &stl[wv][0];
#pragma unroll
    for (int p = 0; p < 16; ++p) gtw[p * GTP + lane] = 0.0f;
    if (lane < 16) stw[lane] = 0.0f;
    const char* xbase = (const char*)xin;
    unsigned laneoff = (unsigned)lane << 1;

    int eA = rowptr[tb],  eAend = rowptr[tb + 8];
    int eB = eAend,       eBend = rowptr[tb + 16];
    int nA = tb,     nendA = 0x7fffffff;
    int nB = tb + 8, nendB = 0x7fffffff;
    float gA = 0.0f, svA = 0.0f, gB = 0.0f, svB = 0.0f;
    if (eA < eAend) {
        nendA = rowptr[nA + 1];
        while (nendA <= eA) { ++nA; nendA = rowptr[nA + 1]; }
    }
    if (eB < eBend) {
        nendB = rowptr[nB + 1];
        while (nendB <= eB) { ++nB; nendB = rowptr[nB + 1]; }
    }
    while (eA < eAend || eB < eBend) {
        int KA = eAend - eA, KB = eBend - eB;
        bool bA = KA >= 8, bB = KB >= 8;
        float vbA[8], nbA[8], vbB[8], nbB[8];
        if (bA) load8(er, eA, xbase, laneoff, vbA, nbA);
        if (bB) load8(er, eB, xbase, laneoff, vbB, nbB);
        if (bA) consume8(vbA, nbA, rowptr, gtw, stw, lane, tb, eAend, eA, nA, nendA, gA, svA);
        else if (KA > 0) tailK(er, xbase, laneoff, rowptr, gtw, stw, lane, tb, KA, eAend, eA, nA, nendA, gA, svA);
        if (bB) consume8(vbB, nbB, rowptr, gtw, stw, lane, tb, eBend, eB, nB, nendB, gB, svB);
        else if (KB > 0) tailK(er, xbase, laneoff, rowptr, gtw, stw, lane, tb, KB, eBend, eB, nB, nendB, gB, svB);
    }

    // ---- MFMA update (wave-private LDS; compiler orders via lgkmcnt) ----
    int L = lane & 15, H = lane >> 4;
    f16x8 a1[2], a2[2];
#pragma unroll
    for (int ks = 0; ks < 2; ++ks) {
        const float* gp = &gt[wv][L][(H << 3) + ks * 32];
        f32x4 g0 = *(const f32x4*)gp;
        f32x4 g1 = *(const f32x4*)(gp + 4);
        f16x8 xv = *(const f16x8*)(xin + (((size_t)(tb + L)) << 6) + (H << 3) + ks * 32);
        f16x8 h1v, h2v;
#pragma unroll
        for (int q = 0; q < 4; ++q) {
            float gq = g0[q], xq = (float)xv[q];
            h1v[q] = (_Float16)(gq + xq);
            h2v[q] = (_Float16)(gq * xq);
        }
#pragma unroll
        for (int q = 0; q < 4; ++q) {
            float gq = g1[q], xq = (float)xv[4 + q];
            h1v[4 + q] = (_Float16)(gq + xq);
            h2v[4 + q] = (_Float16)(gq * xq);
        }
        a1[ks] = h1v; a2[ks] = h2v;
    }
    float sr[4];
#pragma unroll
    for (int r = 0; r < 4; ++r) sr[r] = stl[wv][(H << 2) + r];
#pragma unroll
    for (int nt = 0; nt < 4; ++nt) {
        f16x8 w0 = wfg[(nt * 2 + 0) * 64 + lane];
        f16x8 w1 = wfg[(nt * 2 + 1) * 64 + lane];
        f16x8 w2 = wfg[(8 + nt * 2 + 0) * 64 + lane];
        f16x8 w3 = wfg[(8 + nt * 2 + 1) * 64 + lane];
        float bb1 = b1[nt * 16 + L], bb2 = b2[nt * 16 + L];
        f32x4 acc;
#pragma unroll
        for (int r = 0; r < 4; ++r) acc[r] = (sr[r] + 1.0f) * bb1 + sr[r] * bb2;
        acc = __builtin_amdgcn_mfma_f32_16x16x32_f16(a1[0], w0, acc, 0, 0, 0);
        acc = __builtin_amdgcn_mfma_f32_16x16x32_f16(a1[1], w1, acc, 0, 0, 0);
        acc = __builtin_amdgcn_mfma_f32_16x16x32_f16(a2[0], w2, acc, 0, 0, 0);
        acc = __builtin_amdgcn_mfma_f32_16x16x32_f16(a2[1], w3, acc, 0, 0, 0);
#pragma unroll
        for (int r = 0; r < 4; ++r) {
            float v = acc[r];
            v = v > 0.0f ? v : 0.01f * v;
            int row = tb + (H << 2) + r;
            if (outf) outf[(size_t)row * ostride + nt * 16 + L] = v;
            else      outh[((size_t)row << 6) + nt * 16 + L] = __float2half(v);
        }
        __builtin_amdgcn_sched_barrier(0);
    }
}

extern "C" void kernel_launch(void* const* d_in, const int* in_sizes, int n_in,
                              void* d_out, int out_size, void* d_ws, size_t ws_size,
                              hipStream_t stream) {
    const int* eidx = (const int*)d_in[0];
    const float* w = (const float*)d_in[1];
    const float* emb = (const float*)d_in[2];
    const float* W1 = (const float*)d_in[3];
    const float* b1 = (const float*)d_in[4];
    const float* W2 = (const float*)d_in[5];
    const float* b2 = (const float*)d_in[6];

    int E = in_sizes[1];
    int N = in_sizes[2] / D;
    int L = in_sizes[3] / (D * D);
    const int* frm = eidx;
    const int* to = eidx + E;
    int NFB = (N + NPB - 1) / NPB;

    char* ws = (char*)d_ws;
    size_t off = 0;
    __half* x0 = (__half*)(ws + off);      off += align256((size_t)N * D * 2);
    __half* x1 = (__half*)(ws + off);      off += align256((size_t)N * D * 2);
    int2* er = (int2*)(ws + off);          off += align256((size_t)E * 8);
    int2* ert = (int2*)(ws + off);         off += align256((size_t)E * 8);
    int* rowptr = (int*)(ws + off);        off += align256((size_t)(N + 1) * 4);
    float* dis = (float*)(ws + off);       off += align256((size_t)N * 4);
    unsigned* bcnt = (unsigned*)(ws + off);off += align256((size_t)MAXFB * 4);
    int* fine_base = (int*)(ws + off);     off += align256((size_t)(MAXFB + 1) * 4);
    int* gcur = (int*)(ws + off);          off += align256((size_t)MAXFB * 4);
    f16x8* wf = (f16x8*)(ws + off);        off += align256((size_t)L * 16 * 64 * 16);

    float* out = (float*)d_out;

    hipMemsetAsync(bcnt, 0, (size_t)MAXFB * 4, stream);
    k_wprep<<<(L * 16 * 64 + 255) / 256, 256, 0, stream>>>(W1, W2, L, wf);
    k_hist<<<(E + CHUNK_H - 1) / CHUNK_H, 1024, 0, stream>>>(to, E, NFB, bcnt);
    k_scanb<<<1, 1024, 0, stream>>>(bcnt, NFB, fine_base, gcur);
    k_cfill<<<(E + CHUNK - 1) / CHUNK, 1024, 0, stream>>>(frm, to, w, E, NFB, gcur, ert);
    k_bsort<<<NFB, 256, 0, stream>>>(ert, fine_base, N, NFB, er, rowptr, dis);
    k_prep<<<2048, 256, 0, stream>>>(er, dis, E, emb, x0, out, N);

    __half* xin = x0;
    __half* xalt = x1;
    int nblk = (N + 63) / 64;   // 4 waves/block x 16 nodes/wave
    for (int l = 0; l < L; ++l) {
        float* outf = nullptr;
        __half* outh = xalt;
        int ostride = D;
        if (l == L - 1) {
            outf = out + (size_t)N * D + D;  // output 1, cols 64..127
            outh = nullptr;
            ostride = 2 * D;
        }
        k_flayer<<<nblk, 256, 0, stream>>>(rowptr, er, xin,
                                           wf + (size_t)l * 16 * 64,
                                           b1 + (size_t)l * D, b2 + (size_t)l * D,
                                           N, outf, outh, ostride);
        __half* t = xin; xin = xalt; xalt = t;
    }
}

// Round 12
// 294.412 us; speedup vs baseline: 1.1626x; 1.1626x over previous
//
#include <hip/hip_runtime.h>
#include <hip/hip_fp16.h>
#include <math.h>

#define D 64
#define NPB 64            // nodes per fine bucket
#define MAXFB 1568        // padded bucket-array size (supports N <= 100352)
#define CHUNK 4096        // edges per k_cfill block
#define CHUNK_H 16384     // edges per k_hist block
#define SCAP 2048         // max staged records per bucket in k_bsort
#define GTP 68            // LDS g-tile row stride (272B: 16B-aligned, 2-way banks)

typedef __attribute__((ext_vector_type(8))) _Float16 f16x8;
typedef __attribute__((ext_vector_type(4))) float f32x4;

static inline size_t align256(size_t x) { return (x + 255) & ~(size_t)255; }

// fine-bucket histogram: LDS hist per 16K-edge chunk, few global atomics
__global__ __launch_bounds__(1024) void k_hist(const int* __restrict__ to, int E, int NFB,
                                               unsigned* __restrict__ bcnt) {
    __shared__ unsigned h[MAXFB];
    int t = threadIdx.x;
    for (int i = t; i < MAXFB; i += 1024) h[i] = 0;
    __syncthreads();
    int base = blockIdx.x * CHUNK_H;
    int cnt = E - base; if (cnt > CHUNK_H) cnt = CHUNK_H;
    for (int j = t; j < cnt; j += 1024)
        atomicAdd(&h[((unsigned)to[base + j]) >> 6], 1u);
    __syncthreads();
    for (int i = t; i < NFB; i += 1024) {
        unsigned c = h[i];
        if (c) atomicAdd(&bcnt[i], c);
    }
}

// single-block scan of bcnt -> fine_base[NFB+1], gcur[NFB]
__global__ __launch_bounds__(1024) void k_scanb(const unsigned* __restrict__ bcnt, int NFB,
                                                int* __restrict__ fine_base, int* __restrict__ gcur) {
    __shared__ unsigned sh[1024];
    int t = threadIdx.x;
    int i0 = 2 * t, i1 = 2 * t + 1;
    unsigned a0 = (i0 < NFB) ? bcnt[i0] : 0u;
    unsigned a1 = (i1 < NFB) ? bcnt[i1] : 0u;
    unsigned sum = a0 + a1;
    sh[t] = sum;
    __syncthreads();
    for (int ofs = 1; ofs < 1024; ofs <<= 1) {
        unsigned v = (t >= ofs) ? sh[t - ofs] : 0u;
        __syncthreads();
        sh[t] += v;
        __syncthreads();
    }
    unsigned eb = sh[t] - sum;
    if (i0 < NFB) { fine_base[i0] = (int)eb; gcur[i0] = (int)eb; }
    if (i1 < NFB) { fine_base[i1] = (int)(eb + a0); gcur[i1] = (int)(eb + a0); }
    if (t == 0) fine_base[NFB] = (int)sh[1023];
}

// LDS-staged binned fill: records {frm | (to&63)<<20, w_raw} grouped by fine bucket.
__global__ __launch_bounds__(1024) void k_cfill(
        const int* __restrict__ frm, const int* __restrict__ to, const float* __restrict__ w,
        int E, int NFB, int* __restrict__ gcur, int2* __restrict__ ert) {
    __shared__ int2 stage[CHUNK];
    __shared__ unsigned short sfb[CHUNK];
    __shared__ unsigned hist[MAXFB];
    __shared__ unsigned scanE[MAXFB];
    __shared__ unsigned lbase[MAXFB];
    __shared__ unsigned sh[1024];
    int t = threadIdx.x;
    int base = blockIdx.x * CHUNK;
    int cnt = E - base; if (cnt > CHUNK) cnt = CHUNK;
    for (int b = t; b < MAXFB; b += 1024) hist[b] = 0;
    __syncthreads();
    int2 rec[4]; int fbv[4];
#pragma unroll
    for (int i = 0; i < 4; ++i) {
        int e = base + t + i * 1024;
        fbv[i] = -1;
        if (e < E) {
            int f = frm[e], tt = to[e];
            rec[i].x = f | ((tt & (NPB - 1)) << 20);
            rec[i].y = __float_as_int(w[e]);
            int fb = tt >> 6;
            fbv[i] = fb;
            atomicAdd(&hist[fb], 1u);
        }
    }
    __syncthreads();
    int i0 = 2 * t, i1 = 2 * t + 1;
    unsigned a0 = (i0 < MAXFB) ? hist[i0] : 0u;
    unsigned a1 = (i1 < MAXFB) ? hist[i1] : 0u;
    unsigned sum = a0 + a1;
    sh[t] = sum;
    __syncthreads();
    for (int ofs = 1; ofs < 1024; ofs <<= 1) {
        unsigned v = (t >= ofs) ? sh[t - ofs] : 0u;
        __syncthreads();
        sh[t] += v;
        __syncthreads();
    }
    unsigned eb = sh[t] - sum;
    if (i0 < MAXFB) scanE[i0] = eb;
    if (i1 < MAXFB) scanE[i1] = eb + a0;
    __syncthreads();
    for (int b = t; b < NFB; b += 1024) {
        unsigned c = hist[b];
        if (c) lbase[b] = (unsigned)atomicAdd(&gcur[b], (int)c);
        hist[b] = 0;
    }
    __syncthreads();
#pragma unroll
    for (int i = 0; i < 4; ++i) {
        if (fbv[i] >= 0) {
            unsigned loc = atomicAdd(&hist[fbv[i]], 1u);
            unsigned slot = scanE[fbv[i]] + loc;
            stage[slot] = rec[i];
            sfb[slot] = (unsigned short)fbv[i];
        }
    }
    __syncthreads();
    for (int j = t; j < cnt; j += 1024) {
        int fb = sfb[j];
        ert[(int)lbase[fb] + (j - (int)scanE[fb])] = stage[j];
    }
}

// per-bucket LDS counting sort. Per-node counts == deg -> computes dis here,
// applies dis[to] to the record, strips tl bits, writes rowptr + dis.
__global__ __launch_bounds__(256) void k_bsort(
        const int2* __restrict__ ert, const int* __restrict__ fine_base,
        int N, int NFB, int2* __restrict__ er, int* __restrict__ rowptr,
        float* __restrict__ dis) {
    __shared__ int2 st[SCAP];
    __shared__ int2 st2[SCAP];
    __shared__ unsigned cnt[NPB];
    __shared__ unsigned cbase[NPB];
    __shared__ float dl[NPB];
    int fb = blockIdx.x;
    int b0 = fine_base[fb], b1 = fine_base[fb + 1];
    int len = b1 - b0;
    int t = threadIdx.x;
    if (t < NPB) cnt[t] = 0;
    __syncthreads();
    if (len <= SCAP) {
        for (int j = t; j < len; j += 256) {
            int2 r = ert[b0 + j];
            st[j] = r;
            atomicAdd(&cnt[(r.x >> 20) & 63], 1u);
        }
        __syncthreads();
        if (t < NPB) { unsigned c = cnt[t]; dl[t] = c ? 1.0f / sqrtf((float)c) : 0.0f; }
        __syncthreads();
        if (t == 0) {
            unsigned run = 0;
            for (int i = 0; i < NPB; ++i) { cbase[i] = run; run += cnt[i]; cnt[i] = 0; }
        }
        __syncthreads();
        for (int j = t; j < len; j += 256) {
            int2 r = st[j];
            int n = (r.x >> 20) & 63;
            unsigned loc = atomicAdd(&cnt[n], 1u);
            int2 o;
            o.x = r.x & 0xFFFFF;
            o.y = __float_as_int(__int_as_float(r.y) * dl[n]);
            st2[cbase[n] + loc] = o;
        }
        __syncthreads();
        for (int j = t; j < len; j += 256) er[b0 + j] = st2[j];
    } else {
        for (int j = t; j < len; j += 256)
            atomicAdd(&cnt[(ert[b0 + j].x >> 20) & 63], 1u);
        __syncthreads();
        if (t < NPB) { unsigned c = cnt[t]; dl[t] = c ? 1.0f / sqrtf((float)c) : 0.0f; }
        __syncthreads();
        if (t == 0) {
            unsigned run = 0;
            for (int i = 0; i < NPB; ++i) { cbase[i] = run; run += cnt[i]; cnt[i] = 0; }
        }
        __syncthreads();
        for (int j = t; j < len; j += 256) {
            int2 r = ert[b0 + j];
            int n = (r.x >> 20) & 63;
            unsigned loc = atomicAdd(&cnt[n], 1u);
            int2 o;
            o.x = r.x & 0xFFFFF;
            o.y = __float_as_int(__int_as_float(r.y) * dl[n]);
            er[b0 + (int)cbase[n] + (int)loc] = o;
        }
        __syncthreads();
    }
    int nbase = fb * NPB;
    if (t < NPB && nbase + t < N) {
        rowptr[nbase + t] = b0 + (int)cbase[t];
        dis[nbase + t] = dl[t];
    }
    if (fb == NFB - 1 && t == 0) rowptr[N] = b1;
}

// weight fragment table: wf[layer][mat][nt][ks][lane] = 8 f16 (16B), L1-resident in k_flayer
__global__ void k_wprep(const float* __restrict__ W1, const float* __restrict__ W2,
                        int Lnum, f16x8* __restrict__ wf) {
    int idx = blockIdx.x * blockDim.x + threadIdx.x;   // (layer*16 + frag)*64 + lane
    if (idx >= Lnum * 16 * 64) return;
    int lane = idx & 63;
    int fr = (idx >> 6) & 15;
    int l = idx >> 10;
    int mat = fr >> 3, nt = (fr >> 1) & 3, ks = fr & 1;
    int j = nt * 16 + (lane & 15);
    int kb = ((lane >> 4) << 3) + ks * 32;
    const float* src = (mat ? W2 : W1) + (size_t)l * D * D + j * D + kb;
    f16x8 v;
#pragma unroll
    for (int q = 0; q < 8; ++q) v[q] = (_Float16)src[q];
    wf[idx] = v;
}

// fused setup streaming pass: er.y *= dis[frm]  AND  emb -> x(fp16), out0, out1-cols0..63
__global__ void k_prep(int2* __restrict__ er, const float* __restrict__ dis, int E,
                       const float* __restrict__ emb, __half* __restrict__ x,
                       float* __restrict__ out, int N) {
    int total = E + N * 16;
    int st = gridDim.x * blockDim.x;
    const float4* e4 = (const float4*)emb;
    float4* o4 = (float4*)out;
    __half2* xh = (__half2*)x;
    for (int i = blockIdx.x * blockDim.x + threadIdx.x; i < total; i += st) {
        if (i < E) {
            int2 r = er[i];
            er[i].y = __float_as_int(__int_as_float(r.y) * dis[r.x]);
        } else {
            int j = i - E;
            float4 v = e4[j];
            o4[j] = v;
            int n = j >> 4, c = j & 15;
            o4[(size_t)N * 16 + (size_t)n * 32 + c] = v;
            xh[2 * j]     = __floats2half2_rn(v.x, v.y);
            xh[2 * j + 1] = __floats2half2_rn(v.z, v.w);
        }
    }
}

// fused layer, 2 waves per 16-node tile (TLP): each wave gathers an 8-node
// half (~128 edges) with the 16-deep load pipeline; barrier; each wave runs
// half the MFMA epilogue (nt = half*2 .. half*2+1).
__global__ __launch_bounds__(512) void k_flayer(
        const int* __restrict__ rowptr, const int2* __restrict__ er,
        const __half* __restrict__ xin, const f16x8* __restrict__ wfg,
        const float* __restrict__ b1, const float* __restrict__ b2,
        int N, float* __restrict__ outf, __half* __restrict__ outh, int ostride) {
    __shared__ __align__(16) float gt[4][16][GTP];      // 17.4 KB, per-tile
    __shared__ float stl[4][16];
    int tid = threadIdx.x;
    int lane = tid & 63, wv = tid >> 6;     // wv 0..7
    int pair = wv >> 1;                     // tile in block: 0..3
    int half = wv & 1;                      // 0: nodes 0-7, 1: nodes 8-15
    int tb = (blockIdx.x * 4 + pair) * 16;
    float* gtw = &gt[pair][0][0];
    float* stw = &stl[pair][0];
    if (tb < N) {
        int hb = tb + half * 8;             // this wave's 8-node half
#pragma unroll
        for (int p = 0; p < 8; ++p) gtw[(half * 8 + p) * GTP + lane] = 0.0f;
        if (lane < 8) stw[half * 8 + lane] = 0.0f;
        int e = rowptr[hb], eend = rowptr[hb + 8];
        const __half* xl = xin + lane;
        if (e < eend) {
            int n = hb;
            int nend = rowptr[n + 1];
            while (nend <= e) { ++n; nend = rowptr[n + 1]; }   // skip deg-0 heads
            float gacc = 0.0f, sv = 0.0f;
            while (e < eend) {
                int K = eend - e;
                if (K >= 16) {
                    float vb[16], nb[16];
#pragma unroll
                    for (int k = 0; k < 16; ++k) {
                        int2 r = er[e + k];
                        vb[k] = __half2float(xl[(size_t)r.x << 6]);
                        nb[k] = __int_as_float(r.y);
                    }
#pragma unroll
                    for (int k = 0; k < 16; ++k) {
                        gacc = fmaf(nb[k], vb[k], gacc);
                        sv += nb[k];
                        if (e + k + 1 == nend) {               // wave-uniform
                            gtw[(n - tb) * GTP + lane] = gacc;
                            if (lane == 0) stw[n - tb] = sv;
                            gacc = 0.0f; sv = 0.0f;
                            if (e + k + 1 < eend) {
                                ++n; nend = rowptr[n + 1];
                                while (nend <= e + k + 1) { ++n; nend = rowptr[n + 1]; }
                            } else nend = 0x7fffffff;
                        }
                    }
                    e += 16;
                } else {
                    for (int k = 0; k < K; ++k) {
                        int2 r = er[e + k];
                        float nv = __int_as_float(r.y);
                        gacc = fmaf(nv, __half2float(xl[(size_t)r.x << 6]), gacc);
                        sv += nv;
                        if (e + k + 1 == nend) {
                            gtw[(n - tb) * GTP + lane] = gacc;
                            if (lane == 0) stw[n - tb] = sv;
                            gacc = 0.0f; sv = 0.0f;
                            if (e + k + 1 < eend) {
                                ++n; nend = rowptr[n + 1];
                                while (nend <= e + k + 1) { ++n; nend = rowptr[n + 1]; }
                            } else nend = 0x7fffffff;
                        }
                    }
                    e += K;
                }
            }
        }
    }
    __syncthreads();
    if (tb >= N) return;
    // ---- MFMA epilogue: both waves build A-frags; each does 2 nt blocks ----
    int L = lane & 15, H = lane >> 4;
    f16x8 a1[2], a2[2];
#pragma unroll
    for (int ks = 0; ks < 2; ++ks) {
        const float* gp = &gt[pair][L][(H << 3) + ks * 32];
        f32x4 g0 = *(const f32x4*)gp;
        f32x4 g1 = *(const f32x4*)(gp + 4);
        f16x8 xv = *(const f16x8*)(xin + (((size_t)(tb + L)) << 6) + (H << 3) + ks * 32);
        f16x8 h1v, h2v;
#pragma unroll
        for (int q = 0; q < 4; ++q) {
            float gq = g0[q], xq = (float)xv[q];
            h1v[q] = (_Float16)(gq + xq);
            h2v[q] = (_Float16)(gq * xq);
        }
#pragma unroll
        for (int q = 0; q < 4; ++q) {
            float gq = g1[q], xq = (float)xv[4 + q];
            h1v[4 + q] = (_Float16)(gq + xq);
            h2v[4 + q] = (_Float16)(gq * xq);
        }
        a1[ks] = h1v; a2[ks] = h2v;
    }
    float sr[4];
#pragma unroll
    for (int r = 0; r < 4; ++r) sr[r] = stl[pair][(H << 2) + r];
#pragma unroll
    for (int ntl = 0; ntl < 2; ++ntl) {
        int nt = half * 2 + ntl;
        f16x8 w0 = wfg[(nt * 2 + 0) * 64 + lane];
        f16x8 w1 = wfg[(nt * 2 + 1) * 64 + lane];
        f16x8 w2 = wfg[(8 + nt * 2 + 0) * 64 + lane];
        f16x8 w3 = wfg[(8 + nt * 2 + 1) * 64 + lane];
        float bb1 = b1[nt * 16 + L], bb2 = b2[nt * 16 + L];
        f32x4 acc;
#pragma unroll
        for (int r = 0; r < 4; ++r) acc[r] = (sr[r] + 1.0f) * bb1 + sr[r] * bb2;
        acc = __builtin_amdgcn_mfma_f32_16x16x32_f16(a1[0], w0, acc, 0, 0, 0);
        acc = __builtin_amdgcn_mfma_f32_16x16x32_f16(a1[1], w1, acc, 0, 0, 0);
        acc = __builtin_amdgcn_mfma_f32_16x16x32_f16(a2[0], w2, acc, 0, 0, 0);
        acc = __builtin_amdgcn_mfma_f32_16x16x32_f16(a2[1], w3, acc, 0, 0, 0);
#pragma unroll
        for (int r = 0; r < 4; ++r) {
            float v = acc[r];
            v = v > 0.0f ? v : 0.01f * v;
            int row = tb + (H << 2) + r;
            if (outf) outf[(size_t)row * ostride + nt * 16 + L] = v;
            else      outh[((size_t)row << 6) + nt * 16 + L] = __float2half(v);
        }
    }
}

extern "C" void kernel_launch(void* const* d_in, const int* in_sizes, int n_in,
                              void* d_out, int out_size, void* d_ws, size_t ws_size,
                              hipStream_t stream) {
    const int* eidx = (const int*)d_in[0];
    const float* w = (const float*)d_in[1];
    const float* emb = (const float*)d_in[2];
    const float* W1 = (const float*)d_in[3];
    const float* b1 = (const float*)d_in[4];
    const float* W2 = (const float*)d_in[5];
    const float* b2 = (const float*)d_in[6];

    int E = in_sizes[1];
    int N = in_sizes[2] / D;
    int L = in_sizes[3] / (D * D);
    const int* frm = eidx;
    const int* to = eidx + E;
    int NFB = (N + NPB - 1) / NPB;

    char* ws = (char*)d_ws;
    size_t off = 0;
    __half* x0 = (__half*)(ws + off);      off += align256((size_t)N * D * 2);
    __half* x1 = (__half*)(ws + off);      off += align256((size_t)N * D * 2);
    int2* er = (int2*)(ws + off);          off += align256((size_t)E * 8);
    int2* ert = (int2*)(ws + off);         off += align256((size_t)E * 8);
    int* rowptr = (int*)(ws + off);        off += align256((size_t)(N + 1) * 4);
    float* dis = (float*)(ws + off);       off += align256((size_t)N * 4);
    unsigned* bcnt = (unsigned*)(ws + off);off += align256((size_t)MAXFB * 4);
    int* fine_base = (int*)(ws + off);     off += align256((size_t)(MAXFB + 1) * 4);
    int* gcur = (int*)(ws + off);          off += align256((size_t)MAXFB * 4);
    f16x8* wf = (f16x8*)(ws + off);        off += align256((size_t)L * 16 * 64 * 16);

    float* out = (float*)d_out;

    hipMemsetAsync(bcnt, 0, (size_t)MAXFB * 4, stream);
    k_wprep<<<(L * 16 * 64 + 255) / 256, 256, 0, stream>>>(W1, W2, L, wf);
    k_hist<<<(E + CHUNK_H - 1) / CHUNK_H, 1024, 0, stream>>>(to, E, NFB, bcnt);
    k_scanb<<<1, 1024, 0, stream>>>(bcnt, NFB, fine_base, gcur);
    k_cfill<<<(E + CHUNK - 1) / CHUNK, 1024, 0, stream>>>(frm, to, w, E, NFB, gcur, ert);
    k_bsort<<<NFB, 256, 0, stream>>>(ert, fine_base, N, NFB, er, rowptr, dis);
    k_prep<<<2048, 256, 0, stream>>>(er, dis, E, emb, x0, out, N);

    __half* xin = x0;
    __half* xalt = x1;
    int nblk = (N + 63) / 64;   // 4 tiles/block, 2 waves/tile (512 threads)
    for (int l = 0; l < L; ++l) {
        float* outf = nullptr;
        __half* outh = xalt;
        int ostride = D;
        if (l == L - 1) {
            outf = out + (size_t)N * D + D;  // output 1, cols 64..127
            outh = nullptr;
            ostride = 2 * D;
        }
        k_flayer<<<nblk, 512, 0, stream>>>(rowptr, er, xin,
                                           wf + (size_t)l * 16 * 64,
                                           b1 + (size_t)l * D, b2 + (size_t)l * D,
                                           N, outf, outh, ostride);
        __half* t = xin; xin = xalt; xalt = t;
    }
}

// Round 13
// 263.061 us; speedup vs baseline: 1.3011x; 1.1192x over previous
//
#include <hip/hip_runtime.h>
#include <hip/hip_fp16.h>
#include <math.h>

#define D 64
#define NPB 64            // nodes per fine bucket
#define MAXFB 1568        // padded bucket-array size (supports N <= 100352)
#define CHUNK 4096        // edges per k_cfill block
#define CHUNK_H 16384     // edges per k_hist block
#define SCAP 2048         // max staged records per bucket in k_bsort
#define GTP 68            // LDS g-tile row stride (272B: 16B-aligned, 2-way banks)

typedef __attribute__((ext_vector_type(8))) _Float16 f16x8;
typedef __attribute__((ext_vector_type(4))) float f32x4;

static inline size_t align256(size_t x) { return (x + 255) & ~(size_t)255; }

// fine-bucket histogram: LDS hist per 16K-edge chunk, few global atomics
__global__ __launch_bounds__(1024) void k_hist(const int* __restrict__ to, int E, int NFB,
                                               unsigned* __restrict__ bcnt) {
    __shared__ unsigned h[MAXFB];
    int t = threadIdx.x;
    for (int i = t; i < MAXFB; i += 1024) h[i] = 0;
    __syncthreads();
    int base = blockIdx.x * CHUNK_H;
    int cnt = E - base; if (cnt > CHUNK_H) cnt = CHUNK_H;
    for (int j = t; j < cnt; j += 1024)
        atomicAdd(&h[((unsigned)to[base + j]) >> 6], 1u);
    __syncthreads();
    for (int i = t; i < NFB; i += 1024) {
        unsigned c = h[i];
        if (c) atomicAdd(&bcnt[i], c);
    }
}

// single-block scan of bcnt -> fine_base[NFB+1], gcur[NFB]
__global__ __launch_bounds__(1024) void k_scanb(const unsigned* __restrict__ bcnt, int NFB,
                                                int* __restrict__ fine_base, int* __restrict__ gcur) {
    __shared__ unsigned sh[1024];
    int t = threadIdx.x;
    int i0 = 2 * t, i1 = 2 * t + 1;
    unsigned a0 = (i0 < NFB) ? bcnt[i0] : 0u;
    unsigned a1 = (i1 < NFB) ? bcnt[i1] : 0u;
    unsigned sum = a0 + a1;
    sh[t] = sum;
    __syncthreads();
    for (int ofs = 1; ofs < 1024; ofs <<= 1) {
        unsigned v = (t >= ofs) ? sh[t - ofs] : 0u;
        __syncthreads();
        sh[t] += v;
        __syncthreads();
    }
    unsigned eb = sh[t] - sum;
    if (i0 < NFB) { fine_base[i0] = (int)eb; gcur[i0] = (int)eb; }
    if (i1 < NFB) { fine_base[i1] = (int)(eb + a0); gcur[i1] = (int)(eb + a0); }
    if (t == 0) fine_base[NFB] = (int)sh[1023];
}

// LDS-staged binned fill: records {frm | (to&63)<<20, w_raw} grouped by fine bucket.
__global__ __launch_bounds__(1024) void k_cfill(
        const int* __restrict__ frm, const int* __restrict__ to, const float* __restrict__ w,
        int E, int NFB, int* __restrict__ gcur, int2* __restrict__ ert) {
    __shared__ int2 stage[CHUNK];
    __shared__ unsigned short sfb[CHUNK];
    __shared__ unsigned hist[MAXFB];
    __shared__ unsigned scanE[MAXFB];
    __shared__ unsigned lbase[MAXFB];
    __shared__ unsigned sh[1024];
    int t = threadIdx.x;
    int base = blockIdx.x * CHUNK;
    int cnt = E - base; if (cnt > CHUNK) cnt = CHUNK;
    for (int b = t; b < MAXFB; b += 1024) hist[b] = 0;
    __syncthreads();
    int2 rec[4]; int fbv[4];
#pragma unroll
    for (int i = 0; i < 4; ++i) {
        int e = base + t + i * 1024;
        fbv[i] = -1;
        if (e < E) {
            int f = frm[e], tt = to[e];
            rec[i].x = f | ((tt & (NPB - 1)) << 20);
            rec[i].y = __float_as_int(w[e]);
            int fb = tt >> 6;
            fbv[i] = fb;
            atomicAdd(&hist[fb], 1u);
        }
    }
    __syncthreads();
    int i0 = 2 * t, i1 = 2 * t + 1;
    unsigned a0 = (i0 < MAXFB) ? hist[i0] : 0u;
    unsigned a1 = (i1 < MAXFB) ? hist[i1] : 0u;
    unsigned sum = a0 + a1;
    sh[t] = sum;
    __syncthreads();
    for (int ofs = 1; ofs < 1024; ofs <<= 1) {
        unsigned v = (t >= ofs) ? sh[t - ofs] : 0u;
        __syncthreads();
        sh[t] += v;
        __syncthreads();
    }
    unsigned eb = sh[t] - sum;
    if (i0 < MAXFB) scanE[i0] = eb;
    if (i1 < MAXFB) scanE[i1] = eb + a0;
    __syncthreads();
    for (int b = t; b < NFB; b += 1024) {
        unsigned c = hist[b];
        if (c) lbase[b] = (unsigned)atomicAdd(&gcur[b], (int)c);
        hist[b] = 0;
    }
    __syncthreads();
#pragma unroll
    for (int i = 0; i < 4; ++i) {
        if (fbv[i] >= 0) {
            unsigned loc = atomicAdd(&hist[fbv[i]], 1u);
            unsigned slot = scanE[fbv[i]] + loc;
            stage[slot] = rec[i];
            sfb[slot] = (unsigned short)fbv[i];
        }
    }
    __syncthreads();
    for (int j = t; j < cnt; j += 1024) {
        int fb = sfb[j];
        ert[(int)lbase[fb] + (j - (int)scanE[fb])] = stage[j];
    }
}

// per-bucket LDS counting sort. Per-node counts == deg -> computes dis here,
// applies dis[to] to the record, strips tl bits, writes rowptr + dis.
__global__ __launch_bounds__(256) void k_bsort(
        const int2* __restrict__ ert, const int* __restrict__ fine_base,
        int N, int NFB, int2* __restrict__ er, int* __restrict__ rowptr,
        float* __restrict__ dis) {
    __shared__ int2 st[SCAP];
    __shared__ int2 st2[SCAP];
    __shared__ unsigned cnt[NPB];
    __shared__ unsigned cbase[NPB];
    __shared__ float dl[NPB];
    int fb = blockIdx.x;
    int b0 = fine_base[fb], b1 = fine_base[fb + 1];
    int len = b1 - b0;
    int t = threadIdx.x;
    if (t < NPB) cnt[t] = 0;
    __syncthreads();
    if (len <= SCAP) {
        for (int j = t; j < len; j += 256) {
            int2 r = ert[b0 + j];
            st[j] = r;
            atomicAdd(&cnt[(r.x >> 20) & 63], 1u);
        }
        __syncthreads();
        if (t < NPB) { unsigned c = cnt[t]; dl[t] = c ? 1.0f / sqrtf((float)c) : 0.0f; }
        __syncthreads();
        if (t == 0) {
            unsigned run = 0;
            for (int i = 0; i < NPB; ++i) { cbase[i] = run; run += cnt[i]; cnt[i] = 0; }
        }
        __syncthreads();
        for (int j = t; j < len; j += 256) {
            int2 r = st[j];
            int n = (r.x >> 20) & 63;
            unsigned loc = atomicAdd(&cnt[n], 1u);
            int2 o;
            o.x = r.x & 0xFFFFF;
            o.y = __float_as_int(__int_as_float(r.y) * dl[n]);
            st2[cbase[n] + loc] = o;
        }
        __syncthreads();
        for (int j = t; j < len; j += 256) er[b0 + j] = st2[j];
    } else {
        for (int j = t; j < len; j += 256)
            atomicAdd(&cnt[(ert[b0 + j].x >> 20) & 63], 1u);
        __syncthreads();
        if (t < NPB) { unsigned c = cnt[t]; dl[t] = c ? 1.0f / sqrtf((float)c) : 0.0f; }
        __syncthreads();
        if (t == 0) {
            unsigned run = 0;
            for (int i = 0; i < NPB; ++i) { cbase[i] = run; run += cnt[i]; cnt[i] = 0; }
        }
        __syncthreads();
        for (int j = t; j < len; j += 256) {
            int2 r = ert[b0 + j];
            int n = (r.x >> 20) & 63;
            unsigned loc = atomicAdd(&cnt[n], 1u);
            int2 o;
            o.x = r.x & 0xFFFFF;
            o.y = __float_as_int(__int_as_float(r.y) * dl[n]);
            er[b0 + (int)cbase[n] + (int)loc] = o;
        }
        __syncthreads();
    }
    int nbase = fb * NPB;
    if (t < NPB && nbase + t < N) {
        rowptr[nbase + t] = b0 + (int)cbase[t];
        dis[nbase + t] = dl[t];
    }
    if (fb == NFB - 1 && t == 0) rowptr[N] = b1;
}

// weight fragment table: wf[layer][mat][nt][ks][lane] = 8 f16 (16B), L1-resident in k_flayer
__global__ void k_wprep(const float* __restrict__ W1, const float* __restrict__ W2,
                        int Lnum, f16x8* __restrict__ wf) {
    int idx = blockIdx.x * blockDim.x + threadIdx.x;   // (layer*16 + frag)*64 + lane
    if (idx >= Lnum * 16 * 64) return;
    int lane = idx & 63;
    int fr = (idx >> 6) & 15;
    int l = idx >> 10;
    int mat = fr >> 3, nt = (fr >> 1) & 3, ks = fr & 1;
    int j = nt * 16 + (lane & 15);
    int kb = ((lane >> 4) << 3) + ks * 32;
    const float* src = (mat ? W2 : W1) + (size_t)l * D * D + j * D + kb;
    f16x8 v;
#pragma unroll
    for (int q = 0; q < 8; ++q) v[q] = (_Float16)src[q];
    wf[idx] = v;
}

// fused setup streaming pass: er.y *= dis[frm]  AND  emb -> x(fp16), out0, out1-cols0..63
__global__ void k_prep(int2* __restrict__ er, const float* __restrict__ dis, int E,
                       const float* __restrict__ emb, __half* __restrict__ x,
                       float* __restrict__ out, int N) {
    int total = E + N * 16;
    int st = gridDim.x * blockDim.x;
    const float4* e4 = (const float4*)emb;
    float4* o4 = (float4*)out;
    __half2* xh = (__half2*)x;
    for (int i = blockIdx.x * blockDim.x + threadIdx.x; i < total; i += st) {
        if (i < E) {
            int2 r = er[i];
            er[i].y = __float_as_int(__int_as_float(r.y) * dis[r.x]);
        } else {
            int j = i - E;
            float4 v = e4[j];
            o4[j] = v;
            int n = j >> 4, c = j & 15;
            o4[(size_t)N * 16 + (size_t)n * 32 + c] = v;
            xh[2 * j]     = __floats2half2_rn(v.x, v.y);
            xh[2 * j + 1] = __floats2half2_rn(v.z, v.w);
        }
    }
}

// s[n] = sum of final norms over n's edges (layer-invariant; runs after k_prep)
__global__ void k_sums(const int2* __restrict__ er, const int* __restrict__ rowptr,
                       int N, float* __restrict__ s) {
    int n = blockIdx.x * blockDim.x + threadIdx.x;
    if (n >= N) return;
    int e0 = rowptr[n], e1 = rowptr[n + 1];
    float sv = 0.0f;
    for (int e = e0; e < e1; ++e) sv += __int_as_float(er[e].y);
    s[n] = sv;
}

// fused layer: wave owns a 16-node tile; 16-deep load batch kept LIVE via the
// (256,6) launch-bounds VGPR budget (~85) -> true MLP=16/wave. No sv in loop
// (s precomputed). Flush = 1 ds_write per node; MFMA epilogue from LDS.
__global__ __launch_bounds__(256, 6) void k_flayer(
        const int* __restrict__ rowptr, const int2* __restrict__ er,
        const __half* __restrict__ xin, const f16x8* __restrict__ wfg,
        const float* __restrict__ s,
        const float* __restrict__ b1, const float* __restrict__ b2,
        int N, float* __restrict__ outf, __half* __restrict__ outh, int ostride) {
    __shared__ __align__(16) float gt[4][16][GTP];      // 17.4 KB, wave-private tiles
    __shared__ float stub[4];                            // keep LDS layout aligned
    int tid = threadIdx.x;
    int lane = tid & 63, wv = tid >> 6;
    int tb = (blockIdx.x * 4 + wv) * 16;
    if (tb >= N) return;
    float* gtw = &gt[wv][0][0];
    if (tid == 0) stub[wv] = 0.0f;
#pragma unroll
    for (int p = 0; p < 16; ++p) gtw[p * GTP + lane] = 0.0f;
    int e = rowptr[tb], eend = rowptr[tb + 16];
    const __half* xl = xin + lane;
    if (e < eend) {
        int n = tb;
        int nend = rowptr[n + 1];
        while (nend <= e) { ++n; nend = rowptr[n + 1]; }   // skip deg-0 heads
        float gacc = 0.0f;
        while (e < eend) {
            int K = eend - e;
            if (K >= 16) {
                float vb[16], nb[16];
#pragma unroll
                for (int k = 0; k < 16; ++k) {
                    int2 r = er[e + k];
                    vb[k] = __half2float(xl[(size_t)r.x << 6]);
                    nb[k] = __int_as_float(r.y);
                }
#pragma unroll
                for (int k = 0; k < 16; ++k) {
                    gacc = fmaf(nb[k], vb[k], gacc);
                    if (e + k + 1 == nend) {               // wave-uniform
                        gtw[(n - tb) * GTP + lane] = gacc;
                        gacc = 0.0f;
                        if (e + k + 1 < eend) {
                            ++n; nend = rowptr[n + 1];
                            while (nend <= e + k + 1) { ++n; nend = rowptr[n + 1]; }
                        } else nend = 0x7fffffff;
                    }
                }
                e += 16;
            } else {
                for (int k = 0; k < K; ++k) {
                    int2 r = er[e + k];
                    float nv = __int_as_float(r.y);
                    gacc = fmaf(nv, __half2float(xl[(size_t)r.x << 6]), gacc);
                    if (e + k + 1 == nend) {
                        gtw[(n - tb) * GTP + lane] = gacc;
                        gacc = 0.0f;
                        if (e + k + 1 < eend) {
                            ++n; nend = rowptr[n + 1];
                            while (nend <= e + k + 1) { ++n; nend = rowptr[n + 1]; }
                        } else nend = 0x7fffffff;
                    }
                }
                e += K;
            }
        }
    }
    // ---- MFMA update (wave-private LDS; compiler orders via lgkmcnt) ----
    int L = lane & 15, H = lane >> 4;
    f16x8 a1[2], a2[2];
#pragma unroll
    for (int ks = 0; ks < 2; ++ks) {
        const float* gp = &gt[wv][L][(H << 3) + ks * 32];
        f32x4 g0 = *(const f32x4*)gp;
        f32x4 g1 = *(const f32x4*)(gp + 4);
        f16x8 xv = *(const f16x8*)(xin + (((size_t)(tb + L)) << 6) + (H << 3) + ks * 32);
        f16x8 h1v, h2v;
#pragma unroll
        for (int q = 0; q < 4; ++q) {
            float gq = g0[q], xq = (float)xv[q];
            h1v[q] = (_Float16)(gq + xq);
            h2v[q] = (_Float16)(gq * xq);
        }
#pragma unroll
        for (int q = 0; q < 4; ++q) {
            float gq = g1[q], xq = (float)xv[4 + q];
            h1v[4 + q] = (_Float16)(gq + xq);
            h2v[4 + q] = (_Float16)(gq * xq);
        }
        a1[ks] = h1v; a2[ks] = h2v;
    }
    float sr[4];
#pragma unroll
    for (int r = 0; r < 4; ++r) sr[r] = s[tb + (H << 2) + r];
#pragma unroll
    for (int nt = 0; nt < 4; ++nt) {
        f16x8 w0 = wfg[(nt * 2 + 0) * 64 + lane];
        f16x8 w1 = wfg[(nt * 2 + 1) * 64 + lane];
        f16x8 w2 = wfg[(8 + nt * 2 + 0) * 64 + lane];
        f16x8 w3 = wfg[(8 + nt * 2 + 1) * 64 + lane];
        float bb1 = b1[nt * 16 + L], bb2 = b2[nt * 16 + L];
        f32x4 acc;
#pragma unroll
        for (int r = 0; r < 4; ++r) acc[r] = (sr[r] + 1.0f) * bb1 + sr[r] * bb2;
        acc = __builtin_amdgcn_mfma_f32_16x16x32_f16(a1[0], w0, acc, 0, 0, 0);
        acc = __builtin_amdgcn_mfma_f32_16x16x32_f16(a1[1], w1, acc, 0, 0, 0);
        acc = __builtin_amdgcn_mfma_f32_16x16x32_f16(a2[0], w2, acc, 0, 0, 0);
        acc = __builtin_amdgcn_mfma_f32_16x16x32_f16(a2[1], w3, acc, 0, 0, 0);
#pragma unroll
        for (int r = 0; r < 4; ++r) {
            float v = acc[r];
            v = v > 0.0f ? v : 0.01f * v;
            int row = tb + (H << 2) + r;
            if (outf) outf[(size_t)row * ostride + nt * 16 + L] = v;
            else      outh[((size_t)row << 6) + nt * 16 + L] = __float2half(v);
        }
        __builtin_amdgcn_sched_barrier(0);
    }
}

extern "C" void kernel_launch(void* const* d_in, const int* in_sizes, int n_in,
                              void* d_out, int out_size, void* d_ws, size_t ws_size,
                              hipStream_t stream) {
    const int* eidx = (const int*)d_in[0];
    const float* w = (const float*)d_in[1];
    const float* emb = (const float*)d_in[2];
    const float* W1 = (const float*)d_in[3];
    const float* b1 = (const float*)d_in[4];
    const float* W2 = (const float*)d_in[5];
    const float* b2 = (const float*)d_in[6];

    int E = in_sizes[1];
    int N = in_sizes[2] / D;
    int L = in_sizes[3] / (D * D);
    const int* frm = eidx;
    const int* to = eidx + E;
    int NFB = (N + NPB - 1) / NPB;

    char* ws = (char*)d_ws;
    size_t off = 0;
    __half* x0 = (__half*)(ws + off);      off += align256((size_t)N * D * 2);
    __half* x1 = (__half*)(ws + off);      off += align256((size_t)N * D * 2);
    int2* er = (int2*)(ws + off);          off += align256((size_t)E * 8);
    int2* ert = (int2*)(ws + off);         off += align256((size_t)E * 8);
    int* rowptr = (int*)(ws + off);        off += align256((size_t)(N + 1) * 4);
    float* dis = (float*)(ws + off);       off += align256((size_t)N * 4);
    float* s = (float*)(ws + off);         off += align256((size_t)N * 4);
    unsigned* bcnt = (unsigned*)(ws + off);off += align256((size_t)MAXFB * 4);
    int* fine_base = (int*)(ws + off);     off += align256((size_t)(MAXFB + 1) * 4);
    int* gcur = (int*)(ws + off);          off += align256((size_t)MAXFB * 4);
    f16x8* wf = (f16x8*)(ws + off);        off += align256((size_t)L * 16 * 64 * 16);

    float* out = (float*)d_out;

    hipMemsetAsync(bcnt, 0, (size_t)MAXFB * 4, stream);
    k_wprep<<<(L * 16 * 64 + 255) / 256, 256, 0, stream>>>(W1, W2, L, wf);
    k_hist<<<(E + CHUNK_H - 1) / CHUNK_H, 1024, 0, stream>>>(to, E, NFB, bcnt);
    k_scanb<<<1, 1024, 0, stream>>>(bcnt, NFB, fine_base, gcur);
    k_cfill<<<(E + CHUNK - 1) / CHUNK, 1024, 0, stream>>>(frm, to, w, E, NFB, gcur, ert);
    k_bsort<<<NFB, 256, 0, stream>>>(ert, fine_base, N, NFB, er, rowptr, dis);
    k_prep<<<2048, 256, 0, stream>>>(er, dis, E, emb, x0, out, N);
    k_sums<<<(N + 255) / 256, 256, 0, stream>>>(er, rowptr, N, s);

    __half* xin = x0;
    __half* xalt = x1;
    int nblk = (N + 63) / 64;   // 4 waves/block x 16 nodes/wave
    for (int l = 0; l < L; ++l) {
        float* outf = nullptr;
        __half* outh = xalt;
        int ostride = D;
        if (l == L - 1) {
            outf = out + (size_t)N * D + D;  // output 1, cols 64..127
            outh = nullptr;
            ostride = 2 * D;
        }
        k_flayer<<<nblk, 256, 0, stream>>>(rowptr, er, xin,
                                           wf + (size_t)l * 16 * 64, s,
                                           b1 + (size_t)l * D, b2 + (size_t)l * D,
                                           N, outf, outh, ostride);
        __half* t = xin; xin = xalt; xalt = t;
    }
}

// Round 14
// 239.448 us; speedup vs baseline: 1.4294x; 1.0986x over previous
//
#include <hip/hip_runtime.h>
#include <hip/hip_fp16.h>
#include <math.h>

#define D 64
#define NPB 64            // nodes per fine bucket
#define MAXFB 1568        // padded bucket-array size (supports N <= 100352)
#define CHUNK 4096        // edges per k_cfill block
#define CHUNK_H 16384     // edges per k_hist block
#define SCAP 2048         // max staged records per bucket in k_bsort
#define GTP 68            // LDS g-tile row stride (272B: 16B-aligned, 2-way banks)

typedef __attribute__((ext_vector_type(8))) _Float16 f16x8;
typedef __attribute__((ext_vector_type(4))) float f32x4;

static inline size_t align256(size_t x) { return (x + 255) & ~(size_t)255; }

// fine-bucket histogram: LDS hist per 16K-edge chunk, few global atomics
__global__ __launch_bounds__(1024) void k_hist(const int* __restrict__ to, int E, int NFB,
                                               unsigned* __restrict__ bcnt) {
    __shared__ unsigned h[MAXFB];
    int t = threadIdx.x;
    for (int i = t; i < MAXFB; i += 1024) h[i] = 0;
    __syncthreads();
    int base = blockIdx.x * CHUNK_H;
    int cnt = E - base; if (cnt > CHUNK_H) cnt = CHUNK_H;
    for (int j = t; j < cnt; j += 1024)
        atomicAdd(&h[((unsigned)to[base + j]) >> 6], 1u);
    __syncthreads();
    for (int i = t; i < NFB; i += 1024) {
        unsigned c = h[i];
        if (c) atomicAdd(&bcnt[i], c);
    }
}

// single-block scan of bcnt -> fine_base[NFB+1], gcur[NFB]
__global__ __launch_bounds__(1024) void k_scanb(const unsigned* __restrict__ bcnt, int NFB,
                                                int* __restrict__ fine_base, int* __restrict__ gcur) {
    __shared__ unsigned sh[1024];
    int t = threadIdx.x;
    int i0 = 2 * t, i1 = 2 * t + 1;
    unsigned a0 = (i0 < NFB) ? bcnt[i0] : 0u;
    unsigned a1 = (i1 < NFB) ? bcnt[i1] : 0u;
    unsigned sum = a0 + a1;
    sh[t] = sum;
    __syncthreads();
    for (int ofs = 1; ofs < 1024; ofs <<= 1) {
        unsigned v = (t >= ofs) ? sh[t - ofs] : 0u;
        __syncthreads();
        sh[t] += v;
        __syncthreads();
    }
    unsigned eb = sh[t] - sum;
    if (i0 < NFB) { fine_base[i0] = (int)eb; gcur[i0] = (int)eb; }
    if (i1 < NFB) { fine_base[i1] = (int)(eb + a0); gcur[i1] = (int)(eb + a0); }
    if (t == 0) fine_base[NFB] = (int)sh[1023];
}

// LDS-staged binned fill: records {frm | (to&63)<<20, w_raw} grouped by fine bucket.
__global__ __launch_bounds__(1024) void k_cfill(
        const int* __restrict__ frm, const int* __restrict__ to, const float* __restrict__ w,
        int E, int NFB, int* __restrict__ gcur, int2* __restrict__ ert) {
    __shared__ int2 stage[CHUNK];
    __shared__ unsigned short sfb[CHUNK];
    __shared__ unsigned hist[MAXFB];
    __shared__ unsigned scanE[MAXFB];
    __shared__ unsigned lbase[MAXFB];
    __shared__ unsigned sh[1024];
    int t = threadIdx.x;
    int base = blockIdx.x * CHUNK;
    int cnt = E - base; if (cnt > CHUNK) cnt = CHUNK;
    for (int b = t; b < MAXFB; b += 1024) hist[b] = 0;
    __syncthreads();
    int2 rec[4]; int fbv[4];
#pragma unroll
    for (int i = 0; i < 4; ++i) {
        int e = base + t + i * 1024;
        fbv[i] = -1;
        if (e < E) {
            int f = frm[e], tt = to[e];
            rec[i].x = f | ((tt & (NPB - 1)) << 20);
            rec[i].y = __float_as_int(w[e]);
            int fb = tt >> 6;
            fbv[i] = fb;
            atomicAdd(&hist[fb], 1u);
        }
    }
    __syncthreads();
    int i0 = 2 * t, i1 = 2 * t + 1;
    unsigned a0 = (i0 < MAXFB) ? hist[i0] : 0u;
    unsigned a1 = (i1 < MAXFB) ? hist[i1] : 0u;
    unsigned sum = a0 + a1;
    sh[t] = sum;
    __syncthreads();
    for (int ofs = 1; ofs < 1024; ofs <<= 1) {
        unsigned v = (t >= ofs) ? sh[t - ofs] : 0u;
        __syncthreads();
        sh[t] += v;
        __syncthreads();
    }
    unsigned eb = sh[t] - sum;
    if (i0 < MAXFB) scanE[i0] = eb;
    if (i1 < MAXFB) scanE[i1] = eb + a0;
    __syncthreads();
    for (int b = t; b < NFB; b += 1024) {
        unsigned c = hist[b];
        if (c) lbase[b] = (unsigned)atomicAdd(&gcur[b], (int)c);
        hist[b] = 0;
    }
    __syncthreads();
#pragma unroll
    for (int i = 0; i < 4; ++i) {
        if (fbv[i] >= 0) {
            unsigned loc = atomicAdd(&hist[fbv[i]], 1u);
            unsigned slot = scanE[fbv[i]] + loc;
            stage[slot] = rec[i];
            sfb[slot] = (unsigned short)fbv[i];
        }
    }
    __syncthreads();
    for (int j = t; j < cnt; j += 1024) {
        int fb = sfb[j];
        ert[(int)lbase[fb] + (j - (int)scanE[fb])] = stage[j];
    }
}

// per-bucket LDS counting sort. Per-node counts == deg -> computes dis here,
// applies dis[to] to the record, strips tl bits, writes rowptr + dis.
__global__ __launch_bounds__(256) void k_bsort(
        const int2* __restrict__ ert, const int* __restrict__ fine_base,
        int N, int NFB, int2* __restrict__ er, int* __restrict__ rowptr,
        float* __restrict__ dis) {
    __shared__ int2 st[SCAP];
    __shared__ int2 st2[SCAP];
    __shared__ unsigned cnt[NPB];
    __shared__ unsigned cbase[NPB];
    __shared__ float dl[NPB];
    int fb = blockIdx.x;
    int b0 = fine_base[fb], b1 = fine_base[fb + 1];
    int len = b1 - b0;
    int t = threadIdx.x;
    if (t < NPB) cnt[t] = 0;
    __syncthreads();
    if (len <= SCAP) {
        for (int j = t; j < len; j += 256) {
            int2 r = ert[b0 + j];
            st[j] = r;
            atomicAdd(&cnt[(r.x >> 20) & 63], 1u);
        }
        __syncthreads();
        if (t < NPB) { unsigned c = cnt[t]; dl[t] = c ? 1.0f / sqrtf((float)c) : 0.0f; }
        __syncthreads();
        if (t == 0) {
            unsigned run = 0;
            for (int i = 0; i < NPB; ++i) { cbase[i] = run; run += cnt[i]; cnt[i] = 0; }
        }
        __syncthreads();
        for (int j = t; j < len; j += 256) {
            int2 r = st[j];
            int n = (r.x >> 20) & 63;
            unsigned loc = atomicAdd(&cnt[n], 1u);
            int2 o;
            o.x = r.x & 0xFFFFF;
            o.y = __float_as_int(__int_as_float(r.y) * dl[n]);
            st2[cbase[n] + loc] = o;
        }
        __syncthreads();
        for (int j = t; j < len; j += 256) er[b0 + j] = st2[j];
    } else {
        for (int j = t; j < len; j += 256)
            atomicAdd(&cnt[(ert[b0 + j].x >> 20) & 63], 1u);
        __syncthreads();
        if (t < NPB) { unsigned c = cnt[t]; dl[t] = c ? 1.0f / sqrtf((float)c) : 0.0f; }
        __syncthreads();
        if (t == 0) {
            unsigned run = 0;
            for (int i = 0; i < NPB; ++i) { cbase[i] = run; run += cnt[i]; cnt[i] = 0; }
        }
        __syncthreads();
        for (int j = t; j < len; j += 256) {
            int2 r = ert[b0 + j];
            int n = (r.x >> 20) & 63;
            unsigned loc = atomicAdd(&cnt[n], 1u);
            int2 o;
            o.x = r.x & 0xFFFFF;
            o.y = __float_as_int(__int_as_float(r.y) * dl[n]);
            er[b0 + (int)cbase[n] + (int)loc] = o;
        }
        __syncthreads();
    }
    int nbase = fb * NPB;
    if (t < NPB && nbase + t < N) {
        rowptr[nbase + t] = b0 + (int)cbase[t];
        dis[nbase + t] = dl[t];
    }
    if (fb == NFB - 1 && t == 0) rowptr[N] = b1;
}

// weight fragment table: wf[layer][mat][nt][ks][lane] = 8 f16 (16B), L1-resident in k_flayer
__global__ void k_wprep(const float* __restrict__ W1, const float* __restrict__ W2,
                        int Lnum, f16x8* __restrict__ wf) {
    int idx = blockIdx.x * blockDim.x + threadIdx.x;   // (layer*16 + frag)*64 + lane
    if (idx >= Lnum * 16 * 64) return;
    int lane = idx & 63;
    int fr = (idx >> 6) & 15;
    int l = idx >> 10;
    int mat = fr >> 3, nt = (fr >> 1) & 3, ks = fr & 1;
    int j = nt * 16 + (lane & 15);
    int kb = ((lane >> 4) << 3) + ks * 32;
    const float* src = (mat ? W2 : W1) + (size_t)l * D * D + j * D + kb;
    f16x8 v;
#pragma unroll
    for (int q = 0; q < 8; ++q) v[q] = (_Float16)src[q];
    wf[idx] = v;
}

// fused setup streaming pass: er.y *= dis[frm]  AND  emb -> x(fp16), out0, out1-cols0..63
__global__ void k_prep(int2* __restrict__ er, const float* __restrict__ dis, int E,
                       const float* __restrict__ emb, __half* __restrict__ x,
                       float* __restrict__ out, int N) {
    int total = E + N * 16;
    int st = gridDim.x * blockDim.x;
    const float4* e4 = (const float4*)emb;
    float4* o4 = (float4*)out;
    __half2* xh = (__half2*)x;
    for (int i = blockIdx.x * blockDim.x + threadIdx.x; i < total; i += st) {
        if (i < E) {
            int2 r = er[i];
            er[i].y = __float_as_int(__int_as_float(r.y) * dis[r.x]);
        } else {
            int j = i - E;
            float4 v = e4[j];
            o4[j] = v;
            int n = j >> 4, c = j & 15;
            o4[(size_t)N * 16 + (size_t)n * 32 + c] = v;
            xh[2 * j]     = __floats2half2_rn(v.x, v.y);
            xh[2 * j + 1] = __floats2half2_rn(v.z, v.w);
        }
    }
}

// s[n] = sum of final norms over n's edges (layer-invariant; runs after k_prep)
__global__ void k_sums(const int2* __restrict__ er, const int* __restrict__ rowptr,
                       int N, float* __restrict__ s) {
    int n = blockIdx.x * blockDim.x + threadIdx.x;
    if (n >= N) return;
    int e0 = rowptr[n], e1 = rowptr[n + 1];
    float sv = 0.0f;
    for (int e = e0; e < e1; ++e) sv += __int_as_float(er[e].y);
    s[n] = sv;
}

// flush one node's accumulator: combine even/odd-edge halves, lo lanes write LDS.
__device__ __forceinline__ void flushnode(float* __restrict__ gtw, const int* __restrict__ rowptr,
                                          int tb, int c32, bool hib,
                                          int& n, int& nend, float& g0, float& g1,
                                          int eNext, int lim) {
    float s0 = g0 + __shfl_xor(g0, 32);
    float s1 = g1 + __shfl_xor(g1, 32);
    if (!hib) {
        float2* p = (float2*)&gtw[(n - tb) * GTP + (c32 << 1)];
        float2 v; v.x = s0; v.y = s1;
        *p = v;
    }
    g0 = 0.0f; g1 = 0.0f;
    if (eNext < lim) {
        ++n; nend = rowptr[n + 1];
        while (nend <= eNext) { ++n; nend = rowptr[n + 1]; }
    } else nend = 0x7fffffff;
}

// fused layer, half2-packed dual-edge gather: one VMEM row-load serves TWO
// edges (lanes 0-31 edge e, 32-63 edge e+1; 2 features/lane), records fetched
// as int4 pairs -> 1.0 VMEM instr/edge (was 2.0). fp32 accumulation; node
// flush = shfl_xor(32) combine + float2 LDS write. MFMA epilogue unchanged.
__global__ __launch_bounds__(256, 6) void k_flayer(
        const int* __restrict__ rowptr, const int2* __restrict__ er,
        const __half* __restrict__ xin, const f16x8* __restrict__ wfg,
        const float* __restrict__ s,
        const float* __restrict__ b1, const float* __restrict__ b2,
        int N, float* __restrict__ outf, __half* __restrict__ outh, int ostride) {
    __shared__ __align__(16) float gt[4][16][GTP];      // 17.4 KB, wave-private tiles
    int tid = threadIdx.x;
    int lane = tid & 63, wv = tid >> 6;
    int tb = (blockIdx.x * 4 + wv) * 16;
    if (tb >= N) return;
    float* gtw = &gt[wv][0][0];
#pragma unroll
    for (int p = 0; p < 16; ++p) gtw[p * GTP + lane] = 0.0f;
    int e = rowptr[tb], eend = rowptr[tb + 16];
    const char* xbase = (const char*)xin;
    int c32 = lane & 31;
    bool hib = lane >= 32;
    unsigned coff = (unsigned)c32 << 2;
    if (e < eend) {
        int n = tb;
        int nend = rowptr[n + 1];
        while (nend <= e) { ++n; nend = rowptr[n + 1]; }
        float g0 = 0.0f, g1 = 0.0f;
        // leading odd edge -> even alignment for int4 record loads
        if (e & 1) {
            int2 r = er[e];
            float nv = hib ? 0.0f : __int_as_float(r.y);
            __half2 hv = *(const __half2*)(xbase + ((size_t)(unsigned)r.x << 7) + coff);
            g0 = fmaf(nv, __low2float(hv), g0);
            g1 = fmaf(nv, __high2float(hv), g1);
            if (nend == e + 1)
                flushnode(gtw, rowptr, tb, c32, hib, n, nend, g0, g1, e + 1, eend);
            ++e;
        }
        while (e + 16 <= eend) {
            int4 rc[8];
#pragma unroll
            for (int k = 0; k < 8; ++k) rc[k] = *(const int4*)&er[e + 2 * k];
            __half2 hv[8];
            float nv[8];
#pragma unroll
            for (int k = 0; k < 8; ++k) {
                int f = hib ? rc[k].z : rc[k].x;
                nv[k] = __int_as_float(hib ? rc[k].w : rc[k].y);
                hv[k] = *(const __half2*)(xbase + ((size_t)(unsigned)f << 7) + coff);
            }
#pragma unroll
            for (int k = 0; k < 8; ++k) {
                int ep = e + 2 * k;
                float c0 = nv[k] * __low2float(hv[k]);
                float c1 = nv[k] * __high2float(hv[k]);
                if (nend > ep + 2) {
                    g0 += c0; g1 += c1;
                } else if (nend == ep + 1) {
                    if (!hib) { g0 += c0; g1 += c1; }
                    flushnode(gtw, rowptr, tb, c32, hib, n, nend, g0, g1, ep + 1, eend);
                    if (hib) { g0 += c0; g1 += c1; }
                    if (nend == ep + 2)
                        flushnode(gtw, rowptr, tb, c32, hib, n, nend, g0, g1, ep + 2, eend);
                } else {  // nend == ep + 2
                    g0 += c0; g1 += c1;
                    flushnode(gtw, rowptr, tb, c32, hib, n, nend, g0, g1, ep + 2, eend);
                }
            }
            e += 16;
        }
        // tail pairs
        while (e + 2 <= eend) {
            int4 rc = *(const int4*)&er[e];
            int f = hib ? rc.z : rc.x;
            float nv = __int_as_float(hib ? rc.w : rc.y);
            __half2 hvv = *(const __half2*)(xbase + ((size_t)(unsigned)f << 7) + coff);
            float c0 = nv * __low2float(hvv);
            float c1 = nv * __high2float(hvv);
            if (nend > e + 2) {
                g0 += c0; g1 += c1;
            } else if (nend == e + 1) {
                if (!hib) { g0 += c0; g1 += c1; }
                flushnode(gtw, rowptr, tb, c32, hib, n, nend, g0, g1, e + 1, eend);
                if (hib) { g0 += c0; g1 += c1; }
                if (nend == e + 2)
                    flushnode(gtw, rowptr, tb, c32, hib, n, nend, g0, g1, e + 2, eend);
            } else {
                g0 += c0; g1 += c1;
                flushnode(gtw, rowptr, tb, c32, hib, n, nend, g0, g1, e + 2, eend);
            }
            e += 2;
        }
        // final single edge
        if (e < eend) {
            int2 r = er[e];
            float nv = hib ? 0.0f : __int_as_float(r.y);
            __half2 hvv = *(const __half2*)(xbase + ((size_t)(unsigned)r.x << 7) + coff);
            g0 = fmaf(nv, __low2float(hvv), g0);
            g1 = fmaf(nv, __high2float(hvv), g1);
            flushnode(gtw, rowptr, tb, c32, hib, n, nend, g0, g1, e + 1, eend);
        }
    }
    // ---- MFMA update (wave-private LDS; compiler orders via lgkmcnt) ----
    int L = lane & 15, H = lane >> 4;
    f16x8 a1[2], a2[2];
#pragma unroll
    for (int ks = 0; ks < 2; ++ks) {
        const float* gp = &gt[wv][L][(H << 3) + ks * 32];
        f32x4 g0v = *(const f32x4*)gp;
        f32x4 g1v = *(const f32x4*)(gp + 4);
        f16x8 xv = *(const f16x8*)(xin + (((size_t)(tb + L)) << 6) + (H << 3) + ks * 32);
        f16x8 h1v, h2v;
#pragma unroll
        for (int q = 0; q < 4; ++q) {
            float gq = g0v[q], xq = (float)xv[q];
            h1v[q] = (_Float16)(gq + xq);
            h2v[q] = (_Float16)(gq * xq);
        }
#pragma unroll
        for (int q = 0; q < 4; ++q) {
            float gq = g1v[q], xq = (float)xv[4 + q];
            h1v[4 + q] = (_Float16)(gq + xq);
            h2v[4 + q] = (_Float16)(gq * xq);
        }
        a1[ks] = h1v; a2[ks] = h2v;
    }
    float sr[4];
#pragma unroll
    for (int r = 0; r < 4; ++r) sr[r] = s[tb + (H << 2) + r];
#pragma unroll
    for (int nt = 0; nt < 4; ++nt) {
        f16x8 w0 = wfg[(nt * 2 + 0) * 64 + lane];
        f16x8 w1 = wfg[(nt * 2 + 1) * 64 + lane];
        f16x8 w2 = wfg[(8 + nt * 2 + 0) * 64 + lane];
        f16x8 w3 = wfg[(8 + nt * 2 + 1) * 64 + lane];
        float bb1 = b1[nt * 16 + L], bb2 = b2[nt * 16 + L];
        f32x4 acc;
#pragma unroll
        for (int r = 0; r < 4; ++r) acc[r] = (sr[r] + 1.0f) * bb1 + sr[r] * bb2;
        acc = __builtin_amdgcn_mfma_f32_16x16x32_f16(a1[0], w0, acc, 0, 0, 0);
        acc = __builtin_amdgcn_mfma_f32_16x16x32_f16(a1[1], w1, acc, 0, 0, 0);
        acc = __builtin_amdgcn_mfma_f32_16x16x32_f16(a2[0], w2, acc, 0, 0, 0);
        acc = __builtin_amdgcn_mfma_f32_16x16x32_f16(a2[1], w3, acc, 0, 0, 0);
#pragma unroll
        for (int r = 0; r < 4; ++r) {
            float v = acc[r];
            v = v > 0.0f ? v : 0.01f * v;
            int row = tb + (H << 2) + r;
            if (outf) outf[(size_t)row * ostride + nt * 16 + L] = v;
            else      outh[((size_t)row << 6) + nt * 16 + L] = __float2half(v);
        }
        __builtin_amdgcn_sched_barrier(0);
    }
}

extern "C" void kernel_launch(void* const* d_in, const int* in_sizes, int n_in,
                              void* d_out, int out_size, void* d_ws, size_t ws_size,
                              hipStream_t stream) {
    const int* eidx = (const int*)d_in[0];
    const float* w = (const float*)d_in[1];
    const float* emb = (const float*)d_in[2];
    const float* W1 = (const float*)d_in[3];
    const float* b1 = (const float*)d_in[4];
    const float* W2 = (const float*)d_in[5];
    const float* b2 = (const float*)d_in[6];

    int E = in_sizes[1];
    int N = in_sizes[2] / D;
    int L = in_sizes[3] / (D * D);
    const int* frm = eidx;
    const int* to = eidx + E;
    int NFB = (N + NPB - 1) / NPB;

    char* ws = (char*)d_ws;
    size_t off = 0;
    __half* x0 = (__half*)(ws + off);      off += align256((size_t)N * D * 2);
    __half* x1 = (__half*)(ws + off);      off += align256((size_t)N * D * 2);
    int2* er = (int2*)(ws + off);          off += align256((size_t)E * 8);
    int2* ert = (int2*)(ws + off);         off += align256((size_t)E * 8);
    int* rowptr = (int*)(ws + off);        off += align256((size_t)(N + 1) * 4);
    float* dis = (float*)(ws + off);       off += align256((size_t)N * 4);
    float* s = (float*)(ws + off);         off += align256((size_t)N * 4);
    unsigned* bcnt = (unsigned*)(ws + off);off += align256((size_t)MAXFB * 4);
    int* fine_base = (int*)(ws + off);     off += align256((size_t)(MAXFB + 1) * 4);
    int* gcur = (int*)(ws + off);          off += align256((size_t)MAXFB * 4);
    f16x8* wf = (f16x8*)(ws + off);        off += align256((size_t)L * 16 * 64 * 16);

    float* out = (float*)d_out;

    hipMemsetAsync(bcnt, 0, (size_t)MAXFB * 4, stream);
    k_wprep<<<(L * 16 * 64 + 255) / 256, 256, 0, stream>>>(W1, W2, L, wf);
    k_hist<<<(E + CHUNK_H - 1) / CHUNK_H, 1024, 0, stream>>>(to, E, NFB, bcnt);
    k_scanb<<<1, 1024, 0, stream>>>(bcnt, NFB, fine_base, gcur);
    k_cfill<<<(E + CHUNK - 1) / CHUNK, 1024, 0, stream>>>(frm, to, w, E, NFB, gcur, ert);
    k_bsort<<<NFB, 256, 0, stream>>>(ert, fine_base, N, NFB, er, rowptr, dis);
    k_prep<<<2048, 256, 0, stream>>>(er, dis, E, emb, x0, out, N);
    k_sums<<<(N + 255) / 256, 256, 0, stream>>>(er, rowptr, N, s);

    __half* xin = x0;
    __half* xalt = x1;
    int nblk = (N + 63) / 64;   // 4 waves/block x 16 nodes/wave
    for (int l = 0; l < L; ++l) {
        float* outf = nullptr;
        __half* outh = xalt;
        int ostride = D;
        if (l == L - 1) {
            outf = out + (size_t)N * D + D;  // output 1, cols 64..127
            outh = nullptr;
            ostride = 2 * D;
        }
        k_flayer<<<nblk, 256, 0, stream>>>(rowptr, er, xin,
                                           wf + (size_t)l * 16 * 64, s,
                                           b1 + (size_t)l * D, b2 + (size_t)l * D,
                                           N, outf, outh, ostride);
        __half* t = xin; xin = xalt; xalt = t;
    }
}

// Round 16
// 236.201 us; speedup vs baseline: 1.4491x; 1.0137x over previous
//
#include <hip/hip_runtime.h>
#include <hip/hip_fp16.h>
#include <math.h>

#define D 64
#define NPB 64            // nodes per fine bucket
#define MAXFB 1568        // padded bucket-array size (supports N <= 100352)
#define CHUNK 4096        // edges per k_cfill block
#define CHUNK_H 16384     // edges per k_hist block
#define SCAP 2048         // max staged records per bucket in k_bsort
#define GTP 68            // LDS g-tile row stride (272B: 16B-aligned, 2-way banks)
#define FMASK 0x1FFFFu    // frm bits [16:0]
#define FLAGB 0x800000u   // last-edge-of-node flag (bit 23); tl in bits [22:17]

typedef __attribute__((ext_vector_type(8))) _Float16 f16x8;
typedef __attribute__((ext_vector_type(4))) float f32x4;

static inline size_t align256(size_t x) { return (x + 255) & ~(size_t)255; }

// fine-bucket histogram: LDS hist per 16K-edge chunk, few global atomics
__global__ __launch_bounds__(1024) void k_hist(const int* __restrict__ to, int E, int NFB,
                                               unsigned* __restrict__ bcnt) {
    __shared__ unsigned h[MAXFB];
    int t = threadIdx.x;
    for (int i = t; i < MAXFB; i += 1024) h[i] = 0;
    __syncthreads();
    int base = blockIdx.x * CHUNK_H;
    int cnt = E - base; if (cnt > CHUNK_H) cnt = CHUNK_H;
    for (int j = t; j < cnt; j += 1024)
        atomicAdd(&h[((unsigned)to[base + j]) >> 6], 1u);
    __syncthreads();
    for (int i = t; i < NFB; i += 1024) {
        unsigned c = h[i];
        if (c) atomicAdd(&bcnt[i], c);
    }
}

// single-block scan of bcnt -> fine_base[NFB+1], gcur[NFB]
__global__ __launch_bounds__(1024) void k_scanb(const unsigned* __restrict__ bcnt, int NFB,
                                                int* __restrict__ fine_base, int* __restrict__ gcur) {
    __shared__ unsigned sh[1024];
    int t = threadIdx.x;
    int i0 = 2 * t, i1 = 2 * t + 1;
    unsigned a0 = (i0 < NFB) ? bcnt[i0] : 0u;
    unsigned a1 = (i1 < NFB) ? bcnt[i1] : 0u;
    unsigned sum = a0 + a1;
    sh[t] = sum;
    __syncthreads();
    for (int ofs = 1; ofs < 1024; ofs <<= 1) {
        unsigned v = (t >= ofs) ? sh[t - ofs] : 0u;
        __syncthreads();
        sh[t] += v;
        __syncthreads();
    }
    unsigned eb = sh[t] - sum;
    if (i0 < NFB) { fine_base[i0] = (int)eb; gcur[i0] = (int)eb; }
    if (i1 < NFB) { fine_base[i1] = (int)(eb + a0); gcur[i1] = (int)(eb + a0); }
    if (t == 0) fine_base[NFB] = (int)sh[1023];
}

// LDS-staged binned fill: records {frm | (to&63)<<20, w_raw} grouped by fine bucket.
__global__ __launch_bounds__(1024) void k_cfill(
        const int* __restrict__ frm, const int* __restrict__ to, const float* __restrict__ w,
        int E, int NFB, int* __restrict__ gcur, int2* __restrict__ ert) {
    __shared__ int2 stage[CHUNK];
    __shared__ unsigned short sfb[CHUNK];
    __shared__ unsigned hist[MAXFB];
    __shared__ unsigned scanE[MAXFB];
    __shared__ unsigned lbase[MAXFB];
    __shared__ unsigned sh[1024];
    int t = threadIdx.x;
    int base = blockIdx.x * CHUNK;
    int cnt = E - base; if (cnt > CHUNK) cnt = CHUNK;
    for (int b = t; b < MAXFB; b += 1024) hist[b] = 0;
    __syncthreads();
    int2 rec[4]; int fbv[4];
#pragma unroll
    for (int i = 0; i < 4; ++i) {
        int e = base + t + i * 1024;
        fbv[i] = -1;
        if (e < E) {
            int f = frm[e], tt = to[e];
            rec[i].x = f | ((tt & (NPB - 1)) << 20);
            rec[i].y = __float_as_int(w[e]);
            int fb = tt >> 6;
            fbv[i] = fb;
            atomicAdd(&hist[fb], 1u);
        }
    }
    __syncthreads();
    int i0 = 2 * t, i1 = 2 * t + 1;
    unsigned a0 = (i0 < MAXFB) ? hist[i0] : 0u;
    unsigned a1 = (i1 < MAXFB) ? hist[i1] : 0u;
    unsigned sum = a0 + a1;
    sh[t] = sum;
    __syncthreads();
    for (int ofs = 1; ofs < 1024; ofs <<= 1) {
        unsigned v = (t >= ofs) ? sh[t - ofs] : 0u;
        __syncthreads();
        sh[t] += v;
        __syncthreads();
    }
    unsigned eb = sh[t] - sum;
    if (i0 < MAXFB) scanE[i0] = eb;
    if (i1 < MAXFB) scanE[i1] = eb + a0;
    __syncthreads();
    for (int b = t; b < NFB; b += 1024) {
        unsigned c = hist[b];
        if (c) lbase[b] = (unsigned)atomicAdd(&gcur[b], (int)c);
        hist[b] = 0;
    }
    __syncthreads();
#pragma unroll
    for (int i = 0; i < 4; ++i) {
        if (fbv[i] >= 0) {
            unsigned loc = atomicAdd(&hist[fbv[i]], 1u);
            unsigned slot = scanE[fbv[i]] + loc;
            stage[slot] = rec[i];
            sfb[slot] = (unsigned short)fbv[i];
        }
    }
    __syncthreads();
    for (int j = t; j < cnt; j += 1024) {
        int fb = sfb[j];
        ert[(int)lbase[fb] + (j - (int)scanE[fb])] = stage[j];
    }
}

// per-bucket LDS counting sort -> node-sorted er with SELF-DESCRIBING records:
// o.x = frm | (tl<<17) | (last-edge flag<<23). Also writes rowptr + dis.
__global__ __launch_bounds__(256) void k_bsort(
        const int2* __restrict__ ert, const int* __restrict__ fine_base,
        int N, int NFB, int2* __restrict__ er, int* __restrict__ rowptr,
        float* __restrict__ dis) {
    __shared__ int2 st[SCAP];
    __shared__ int2 st2[SCAP];
    __shared__ unsigned cnt[NPB];
    __shared__ unsigned dcount[NPB];
    __shared__ unsigned cbase[NPB];
    __shared__ float dl[NPB];
    int fb = blockIdx.x;
    int b0 = fine_base[fb], b1 = fine_base[fb + 1];
    int len = b1 - b0;
    int t = threadIdx.x;
    if (t < NPB) cnt[t] = 0;
    __syncthreads();
    if (len <= SCAP) {
        for (int j = t; j < len; j += 256) {
            int2 r = ert[b0 + j];
            st[j] = r;
            atomicAdd(&cnt[(r.x >> 20) & 63], 1u);
        }
        __syncthreads();
        if (t < NPB) {
            unsigned c = cnt[t];
            dcount[t] = c;
            dl[t] = c ? 1.0f / sqrtf((float)c) : 0.0f;
        }
        __syncthreads();
        if (t == 0) {
            unsigned run = 0;
            for (int i = 0; i < NPB; ++i) { cbase[i] = run; run += cnt[i]; cnt[i] = 0; }
        }
        __syncthreads();
        for (int j = t; j < len; j += 256) {
            int2 r = st[j];
            int n = (r.x >> 20) & 63;
            unsigned loc = atomicAdd(&cnt[n], 1u);
            int2 o;
            o.x = (int)((r.x & FMASK) | ((unsigned)n << 17) |
                        ((loc == dcount[n] - 1) ? FLAGB : 0u));
            o.y = __float_as_int(__int_as_float(r.y) * dl[n]);
            st2[cbase[n] + loc] = o;
        }
        __syncthreads();
        for (int j = t; j < len; j += 256) er[b0 + j] = st2[j];
    } else {
        for (int j = t; j < len; j += 256)
            atomicAdd(&cnt[(ert[b0 + j].x >> 20) & 63], 1u);
        __syncthreads();
        if (t < NPB) {
            unsigned c = cnt[t];
            dcount[t] = c;
            dl[t] = c ? 1.0f / sqrtf((float)c) : 0.0f;
        }
        __syncthreads();
        if (t == 0) {
            unsigned run = 0;
            for (int i = 0; i < NPB; ++i) { cbase[i] = run; run += cnt[i]; cnt[i] = 0; }
        }
        __syncthreads();
        for (int j = t; j < len; j += 256) {
            int2 r = ert[b0 + j];
            int n = (r.x >> 20) & 63;
            unsigned loc = atomicAdd(&cnt[n], 1u);
            int2 o;
            o.x = (int)((r.x & FMASK) | ((unsigned)n << 17) |
                        ((loc == dcount[n] - 1) ? FLAGB : 0u));
            o.y = __float_as_int(__int_as_float(r.y) * dl[n]);
            er[b0 + (int)cbase[n] + (int)loc] = o;
        }
        __syncthreads();
    }
    int nbase = fb * NPB;
    if (t < NPB && nbase + t < N) {
        rowptr[nbase + t] = b0 + (int)cbase[t];
        dis[nbase + t] = dl[t];
    }
    if (fb == NFB - 1 && t == 0) rowptr[N] = b1;
}

// weight fragment table: wf[layer][mat][nt][ks][lane] = 8 f16 (16B), L1-resident in k_flayer
__global__ void k_wprep(const float* __restrict__ W1, const float* __restrict__ W2,
                        int Lnum, f16x8* __restrict__ wf) {
    int idx = blockIdx.x * blockDim.x + threadIdx.x;   // (layer*16 + frag)*64 + lane
    if (idx >= Lnum * 16 * 64) return;
    int lane = idx & 63;
    int fr = (idx >> 6) & 15;
    int l = idx >> 10;
    int mat = fr >> 3, nt = (fr >> 1) & 3, ks = fr & 1;
    int j = nt * 16 + (lane & 15);
    int kb = ((lane >> 4) << 3) + ks * 32;
    const float* src = (mat ? W2 : W1) + (size_t)l * D * D + j * D + kb;
    f16x8 v;
#pragma unroll
    for (int q = 0; q < 8; ++q) v[q] = (_Float16)src[q];
    wf[idx] = v;
}

// fused setup streaming pass: er.y *= dis[frm]  AND  emb -> x(fp16), out0, out1-cols0..63
__global__ void k_prep(int2* __restrict__ er, const float* __restrict__ dis, int E,
                       const float* __restrict__ emb, __half* __restrict__ x,
                       float* __restrict__ out, int N) {
    int total = E + N * 16;
    int st = gridDim.x * blockDim.x;
    const float4* e4 = (const float4*)emb;
    float4* o4 = (float4*)out;
    __half2* xh = (__half2*)x;
    for (int i = blockIdx.x * blockDim.x + threadIdx.x; i < total; i += st) {
        if (i < E) {
            int2 r = er[i];
            er[i].y = __float_as_int(__int_as_float(r.y) * dis[(unsigned)r.x & FMASK]);
        } else {
            int j = i - E;
            float4 v = e4[j];
            o4[j] = v;
            int n = j >> 4, c = j & 15;
            o4[(size_t)N * 16 + (size_t)n * 32 + c] = v;
            xh[2 * j]     = __floats2half2_rn(v.x, v.y);
            xh[2 * j + 1] = __floats2half2_rn(v.z, v.w);
        }
    }
}

// s[n] = sum of final norms over n's edges (layer-invariant; runs after k_prep)
__global__ void k_sums(const int2* __restrict__ er, const int* __restrict__ rowptr,
                       int N, float* __restrict__ s) {
    int n = blockIdx.x * blockDim.x + threadIdx.x;
    if (n >= N) return;
    int e0 = rowptr[n], e1 = rowptr[n + 1];
    float sv = 0.0f;
    for (int e = e0; e < e1; ++e) sv += __int_as_float(er[e].y);
    s[n] = sv;
}

// flush: combine even/odd halves, lo lanes write float2 to LDS row tl, reset.
// tl here is TILE-LOCAL (0..15): caller passes (rx>>17)&15 (bucket-local & 15),
// valid because each wave's edge range only contains its own 16 nodes.
__device__ __forceinline__ void flushf(float* __restrict__ gtw, int tl, int c32, bool hib,
                                       float& g0, float& g1) {
    float s0 = g0 + __shfl_xor(g0, 32);
    float s1 = g1 + __shfl_xor(g1, 32);
    if (!hib) {
        float2* p = (float2*)&gtw[tl * GTP + (c32 << 1)];
        float2 v; v.x = s0; v.y = s1;
        *p = v;
    }
    g0 = 0.0f; g1 = 0.0f;
}

// fused layer, flag-driven: records carry {frm, tl, last-edge flag} so the
// gather loop has NO rowptr reads / node-state tracking — accumulate, and on a
// (wave-uniform) flag bit combine+write to LDS row tl&15. half2 dual-edge
// packing (1 VMEM/edge). MFMA epilogue from LDS.
__global__ __launch_bounds__(256, 6) void k_flayer(
        const int* __restrict__ rowptr, const int2* __restrict__ er,
        const __half* __restrict__ xin, const f16x8* __restrict__ wfg,
        const float* __restrict__ s,
        const float* __restrict__ b1, const float* __restrict__ b2,
        int N, float* __restrict__ outf, __half* __restrict__ outh, int ostride) {
    __shared__ __align__(16) float gt[4][16][GTP];      // 17.4 KB, wave-private tiles
    int tid = threadIdx.x;
    int lane = tid & 63, wv = tid >> 6;
    int tb = (blockIdx.x * 4 + wv) * 16;
    if (tb >= N) return;
    float* gtw = &gt[wv][0][0];
#pragma unroll
    for (int p = 0; p < 16; ++p) gtw[p * GTP + lane] = 0.0f;
    int e = rowptr[tb], eend = rowptr[tb + 16];
    const char* xbase = (const char*)xin;
    int c32 = lane & 31;
    bool hib = lane >= 32;
    unsigned coff = (unsigned)c32 << 2;
    if (e < eend) {
        float g0 = 0.0f, g1 = 0.0f;
        // leading odd edge -> even alignment for int4 record loads
        if (e & 1) {
            int2 r = er[e];
            unsigned rx = (unsigned)r.x;
            float nv = hib ? 0.0f : __int_as_float(r.y);
            __half2 hv = *(const __half2*)(xbase + ((size_t)(rx & FMASK) << 7) + coff);
            g0 = fmaf(nv, __low2float(hv), g0);
            g1 = fmaf(nv, __high2float(hv), g1);
            if (rx & FLAGB) flushf(gtw, (rx >> 17) & 15, c32, hib, g0, g1);
            ++e;
        }
        while (e + 16 <= eend) {
            int4 rc[8];
#pragma unroll
            for (int k = 0; k < 8; ++k) rc[k] = *(const int4*)&er[e + 2 * k];
            __half2 hv[8];
            float nv[8];
#pragma unroll
            for (int k = 0; k < 8; ++k) {
                unsigned rx = (unsigned)(hib ? rc[k].z : rc[k].x);
                nv[k] = __int_as_float(hib ? rc[k].w : rc[k].y);
                hv[k] = *(const __half2*)(xbase + ((size_t)(rx & FMASK) << 7) + coff);
            }
#pragma unroll
            for (int k = 0; k < 8; ++k) {
                unsigned rxl = (unsigned)rc[k].x, rxh = (unsigned)rc[k].z;
                float c0 = nv[k] * __low2float(hv[k]);
                float c1 = nv[k] * __high2float(hv[k]);
                if (!((rxl | rxh) & FLAGB)) {          // fast path, wave-uniform
                    g0 += c0; g1 += c1;
                } else if (rxl & FLAGB) {
                    if (!hib) { g0 += c0; g1 += c1; }
                    flushf(gtw, (rxl >> 17) & 15, c32, hib, g0, g1);
                    if (hib) { g0 += c0; g1 += c1; }
                    if (rxh & FLAGB) flushf(gtw, (rxh >> 17) & 15, c32, hib, g0, g1);
                } else {                               // only hi flagged
                    g0 += c0; g1 += c1;
                    flushf(gtw, (rxh >> 17) & 15, c32, hib, g0, g1);
                }
            }
            e += 16;
        }
        // tail pairs
        while (e + 2 <= eend) {
            int4 rc = *(const int4*)&er[e];
            unsigned rxl = (unsigned)rc.x, rxh = (unsigned)rc.z;
            unsigned rx = hib ? rxh : rxl;
            float nv = __int_as_float(hib ? rc.w : rc.y);
            __half2 hvv = *(const __half2*)(xbase + ((size_t)(rx & FMASK) << 7) + coff);
            float c0 = nv * __low2float(hvv);
            float c1 = nv * __high2float(hvv);
            if (!((rxl | rxh) & FLAGB)) {
                g0 += c0; g1 += c1;
            } else if (rxl & FLAGB) {
                if (!hib) { g0 += c0; g1 += c1; }
                flushf(gtw, (rxl >> 17) & 15, c32, hib, g0, g1);
                if (hib) { g0 += c0; g1 += c1; }
                if (rxh & FLAGB) flushf(gtw, (rxh >> 17) & 15, c32, hib, g0, g1);
            } else {
                g0 += c0; g1 += c1;
                flushf(gtw, (rxh >> 17) & 15, c32, hib, g0, g1);
            }
            e += 2;
        }
        // final single edge
        if (e < eend) {
            int2 r = er[e];
            unsigned rx = (unsigned)r.x;
            float nv = hib ? 0.0f : __int_as_float(r.y);
            __half2 hvv = *(const __half2*)(xbase + ((size_t)(rx & FMASK) << 7) + coff);
            g0 = fmaf(nv, __low2float(hvv), g0);
            g1 = fmaf(nv, __high2float(hvv), g1);
            if (rx & FLAGB) flushf(gtw, (rx >> 17) & 15, c32, hib, g0, g1);
        }
    }
    // ---- MFMA update (wave-private LDS; compiler orders via lgkmcnt) ----
    int L = lane & 15, H = lane >> 4;
    f16x8 a1[2], a2[2];
#pragma unroll
    for (int ks = 0; ks < 2; ++ks) {
        const float* gp = &gt[wv][L][(H << 3) + ks * 32];
        f32x4 g0v = *(const f32x4*)gp;
        f32x4 g1v = *(const f32x4*)(gp + 4);
        f16x8 xv = *(const f16x8*)(xin + (((size_t)(tb + L)) << 6) + (H << 3) + ks * 32);
        f16x8 h1v, h2v;
#pragma unroll
        for (int q = 0; q < 4; ++q) {
            float gq = g0v[q], xq = (float)xv[q];
            h1v[q] = (_Float16)(gq + xq);
            h2v[q] = (_Float16)(gq * xq);
        }
#pragma unroll
        for (int q = 0; q < 4; ++q) {
            float gq = g1v[q], xq = (float)xv[4 + q];
            h1v[4 + q] = (_Float16)(gq + xq);
            h2v[4 + q] = (_Float16)(gq * xq);
        }
        a1[ks] = h1v; a2[ks] = h2v;
    }
    float sr[4];
#pragma unroll
    for (int r = 0; r < 4; ++r) sr[r] = s[tb + (H << 2) + r];
#pragma unroll
    for (int nt = 0; nt < 4; ++nt) {
        f16x8 w0 = wfg[(nt * 2 + 0) * 64 + lane];
        f16x8 w1 = wfg[(nt * 2 + 1) * 64 + lane];
        f16x8 w2 = wfg[(8 + nt * 2 + 0) * 64 + lane];
        f16x8 w3 = wfg[(8 + nt * 2 + 1) * 64 + lane];
        float bb1 = b1[nt * 16 + L], bb2 = b2[nt * 16 + L];
        f32x4 acc;
#pragma unroll
        for (int r = 0; r < 4; ++r) acc[r] = (sr[r] + 1.0f) * bb1 + sr[r] * bb2;
        acc = __builtin_amdgcn_mfma_f32_16x16x32_f16(a1[0], w0, acc, 0, 0, 0);
        acc = __builtin_amdgcn_mfma_f32_16x16x32_f16(a1[1], w1, acc, 0, 0, 0);
        acc = __builtin_amdgcn_mfma_f32_16x16x32_f16(a2[0], w2, acc, 0, 0, 0);
        acc = __builtin_amdgcn_mfma_f32_16x16x32_f16(a2[1], w3, acc, 0, 0, 0);
#pragma unroll
        for (int r = 0; r < 4; ++r) {
            float v = acc[r];
            v = v > 0.0f ? v : 0.01f * v;
            int row = tb + (H << 2) + r;
            if (outf) outf[(size_t)row * ostride + nt * 16 + L] = v;
            else      outh[((size_t)row << 6) + nt * 16 + L] = __float2half(v);
        }
        __builtin_amdgcn_sched_barrier(0);
    }
}

extern "C" void kernel_launch(void* const* d_in, const int* in_sizes, int n_in,
                              void* d_out, int out_size, void* d_ws, size_t ws_size,
                              hipStream_t stream) {
    const int* eidx = (const int*)d_in[0];
    const float* w = (const float*)d_in[1];
    const float* emb = (const float*)d_in[2];
    const float* W1 = (const float*)d_in[3];
    const float* b1 = (const float*)d_in[4];
    const float* W2 = (const float*)d_in[5];
    const float* b2 = (const float*)d_in[6];

    int E = in_sizes[1];
    int N = in_sizes[2] / D;
    int L = in_sizes[3] / (D * D);
    const int* frm = eidx;
    const int* to = eidx + E;
    int NFB = (N + NPB - 1) / NPB;

    char* ws = (char*)d_ws;
    size_t off = 0;
    __half* x0 = (__half*)(ws + off);      off += align256((size_t)N * D * 2);
    __half* x1 = (__half*)(ws + off);      off += align256((size_t)N * D * 2);
    int2* er = (int2*)(ws + off);          off += align256((size_t)E * 8);
    int2* ert = (int2*)(ws + off);         off += align256((size_t)E * 8);
    int* rowptr = (int*)(ws + off);        off += align256((size_t)(N + 1) * 4);
    float* dis = (float*)(ws + off);       off += align256((size_t)N * 4);
    float* s = (float*)(ws + off);         off += align256((size_t)N * 4);
    unsigned* bcnt = (unsigned*)(ws + off);off += align256((size_t)MAXFB * 4);
    int* fine_base = (int*)(ws + off);     off += align256((size_t)(MAXFB + 1) * 4);
    int* gcur = (int*)(ws + off);          off += align256((size_t)MAXFB * 4);
    f16x8* wf = (f16x8*)(ws + off);        off += align256((size_t)L * 16 * 64 * 16);

    float* out = (float*)d_out;

    hipMemsetAsync(bcnt, 0, (size_t)MAXFB * 4, stream);
    k_wprep<<<(L * 16 * 64 + 255) / 256, 256, 0, stream>>>(W1, W2, L, wf);
    k_hist<<<(E + CHUNK_H - 1) / CHUNK_H, 1024, 0, stream>>>(to, E, NFB, bcnt);
    k_scanb<<<1, 1024, 0, stream>>>(bcnt, NFB, fine_base, gcur);
    k_cfill<<<(E + CHUNK - 1) / CHUNK, 1024, 0, stream>>>(frm, to, w, E, NFB, gcur, ert);
    k_bsort<<<NFB, 256, 0, stream>>>(ert, fine_base, N, NFB, er, rowptr, dis);
    k_prep<<<2048, 256, 0, stream>>>(er, dis, E, emb, x0, out, N);
    k_sums<<<(N + 255) / 256, 256, 0, stream>>>(er, rowptr, N, s);

    __half* xin = x0;
    __half* xalt = x1;
    int nblk = (N + 63) / 64;   // 4 waves/block x 16 nodes/wave (1 bucket/block)
    for (int l = 0; l < L; ++l) {
        float* outf = nullptr;
        __half* outh = xalt;
        int ostride = D;
        if (l == L - 1) {
            outf = out + (size_t)N * D + D;  // output 1, cols 64..127
            outh = nullptr;
            ostride = 2 * D;
        }
        k_flayer<<<nblk, 256, 0, stream>>>(rowptr, er, xin,
                                           wf + (size_t)l * 16 * 64, s,
                                           b1 + (size_t)l * D, b2 + (size_t)l * D,
                                           N, outf, outh, ostride);
        __half* t = xin; xin = xalt; xalt = t;
    }
}

// Round 17
// 207.525 us; speedup vs baseline: 1.6493x; 1.1382x over previous
//
#include <hip/hip_runtime.h>
#include <hip/hip_fp16.h>
#include <math.h>

#define D 64
#define NPB 64            // nodes per fine bucket
#define MAXFB 1568        // padded bucket-array size (supports N <= 100352)
#define CHUNK 4096        // edges per k_cfill block
#define CHUNK_H 16384     // edges per k_hist block
#define SCAP 2048         // max staged records per bucket in k_bsort
#define GTP 68            // LDS g-tile row stride (272B: 16B-aligned, 2-way banks)
#define FMASK 0x1FFFFu    // frm bits [16:0] (cfill-stage records)

typedef __attribute__((ext_vector_type(8))) _Float16 f16x8;
typedef __attribute__((ext_vector_type(4))) float f32x4;

static inline size_t align256(size_t x) { return (x + 255) & ~(size_t)255; }

// fine-bucket histogram: LDS hist per 16K-edge chunk, few global atomics
__global__ __launch_bounds__(1024) void k_hist(const int* __restrict__ to, int E, int NFB,
                                               unsigned* __restrict__ bcnt) {
    __shared__ unsigned h[MAXFB];
    int t = threadIdx.x;
    for (int i = t; i < MAXFB; i += 1024) h[i] = 0;
    __syncthreads();
    int base = blockIdx.x * CHUNK_H;
    int cnt = E - base; if (cnt > CHUNK_H) cnt = CHUNK_H;
    for (int j = t; j < cnt; j += 1024)
        atomicAdd(&h[((unsigned)to[base + j]) >> 6], 1u);
    __syncthreads();
    for (int i = t; i < NFB; i += 1024) {
        unsigned c = h[i];
        if (c) atomicAdd(&bcnt[i], c);
    }
}

// single-block scan of bcnt -> fine_base[NFB+1], gcur[NFB]
__global__ __launch_bounds__(1024) void k_scanb(const unsigned* __restrict__ bcnt, int NFB,
                                                int* __restrict__ fine_base, int* __restrict__ gcur) {
    __shared__ unsigned sh[1024];
    int t = threadIdx.x;
    int i0 = 2 * t, i1 = 2 * t + 1;
    unsigned a0 = (i0 < NFB) ? bcnt[i0] : 0u;
    unsigned a1 = (i1 < NFB) ? bcnt[i1] : 0u;
    unsigned sum = a0 + a1;
    sh[t] = sum;
    __syncthreads();
    for (int ofs = 1; ofs < 1024; ofs <<= 1) {
        unsigned v = (t >= ofs) ? sh[t - ofs] : 0u;
        __syncthreads();
        sh[t] += v;
        __syncthreads();
    }
    unsigned eb = sh[t] - sum;
    if (i0 < NFB) { fine_base[i0] = (int)eb; gcur[i0] = (int)eb; }
    if (i1 < NFB) { fine_base[i1] = (int)(eb + a0); gcur[i1] = (int)(eb + a0); }
    if (t == 0) fine_base[NFB] = (int)sh[1023];
}

// LDS-staged binned fill: records {frm | (to&63)<<20, w_raw} grouped by fine bucket.
__global__ __launch_bounds__(1024) void k_cfill(
        const int* __restrict__ frm, const int* __restrict__ to, const float* __restrict__ w,
        int E, int NFB, int* __restrict__ gcur, int2* __restrict__ ert) {
    __shared__ int2 stage[CHUNK];
    __shared__ unsigned short sfb[CHUNK];
    __shared__ unsigned hist[MAXFB];
    __shared__ unsigned scanE[MAXFB];
    __shared__ unsigned lbase[MAXFB];
    __shared__ unsigned sh[1024];
    int t = threadIdx.x;
    int base = blockIdx.x * CHUNK;
    int cnt = E - base; if (cnt > CHUNK) cnt = CHUNK;
    for (int b = t; b < MAXFB; b += 1024) hist[b] = 0;
    __syncthreads();
    int2 rec[4]; int fbv[4];
#pragma unroll
    for (int i = 0; i < 4; ++i) {
        int e = base + t + i * 1024;
        fbv[i] = -1;
        if (e < E) {
            int f = frm[e], tt = to[e];
            rec[i].x = f | ((tt & (NPB - 1)) << 20);
            rec[i].y = __float_as_int(w[e]);
            int fb = tt >> 6;
            fbv[i] = fb;
            atomicAdd(&hist[fb], 1u);
        }
    }
    __syncthreads();
    int i0 = 2 * t, i1 = 2 * t + 1;
    unsigned a0 = (i0 < MAXFB) ? hist[i0] : 0u;
    unsigned a1 = (i1 < MAXFB) ? hist[i1] : 0u;
    unsigned sum = a0 + a1;
    sh[t] = sum;
    __syncthreads();
    for (int ofs = 1; ofs < 1024; ofs <<= 1) {
        unsigned v = (t >= ofs) ? sh[t - ofs] : 0u;
        __syncthreads();
        sh[t] += v;
        __syncthreads();
    }
    unsigned eb = sh[t] - sum;
    if (i0 < MAXFB) scanE[i0] = eb;
    if (i1 < MAXFB) scanE[i1] = eb + a0;
    __syncthreads();
    for (int b = t; b < NFB; b += 1024) {
        unsigned c = hist[b];
        if (c) lbase[b] = (unsigned)atomicAdd(&gcur[b], (int)c);
        hist[b] = 0;
    }
    __syncthreads();
#pragma unroll
    for (int i = 0; i < 4; ++i) {
        if (fbv[i] >= 0) {
            unsigned loc = atomicAdd(&hist[fbv[i]], 1u);
            unsigned slot = scanE[fbv[i]] + loc;
            stage[slot] = rec[i];
            sfb[slot] = (unsigned short)fbv[i];
        }
    }
    __syncthreads();
    for (int j = t; j < cnt; j += 1024) {
        int fb = sfb[j];
        ert[(int)lbase[fb] + (j - (int)scanE[fb])] = stage[j];
    }
}

// per-bucket LDS counting sort -> node-sorted er with SELF-DESCRIBING records:
// o.x = (frm<<7) | ((n&15)<<1) | last-edge-flag. (frm<<7 = pre-baked byte
// offset into the 128B fp16 x rows.) Also writes rowptr + dis.
__global__ __launch_bounds__(256) void k_bsort(
        const int2* __restrict__ ert, const int* __restrict__ fine_base,
        int N, int NFB, int2* __restrict__ er, int* __restrict__ rowptr,
        float* __restrict__ dis) {
    __shared__ int2 st[SCAP];
    __shared__ int2 st2[SCAP];
    __shared__ unsigned cnt[NPB];
    __shared__ unsigned dcount[NPB];
    __shared__ unsigned cbase[NPB];
    __shared__ float dl[NPB];
    int fb = blockIdx.x;
    int b0 = fine_base[fb], b1 = fine_base[fb + 1];
    int len = b1 - b0;
    int t = threadIdx.x;
    if (t < NPB) cnt[t] = 0;
    __syncthreads();
    if (len <= SCAP) {
        for (int j = t; j < len; j += 256) {
            int2 r = ert[b0 + j];
            st[j] = r;
            atomicAdd(&cnt[(r.x >> 20) & 63], 1u);
        }
        __syncthreads();
        if (t < NPB) {
            unsigned c = cnt[t];
            dcount[t] = c;
            dl[t] = c ? 1.0f / sqrtf((float)c) : 0.0f;
        }
        __syncthreads();
        if (t == 0) {
            unsigned run = 0;
            for (int i = 0; i < NPB; ++i) { cbase[i] = run; run += cnt[i]; cnt[i] = 0; }
        }
        __syncthreads();
        for (int j = t; j < len; j += 256) {
            int2 r = st[j];
            int n = (r.x >> 20) & 63;
            unsigned loc = atomicAdd(&cnt[n], 1u);
            int2 o;
            o.x = (int)((((unsigned)r.x & FMASK) << 7) | (((unsigned)n & 15u) << 1) |
                        ((loc == dcount[n] - 1) ? 1u : 0u));
            o.y = __float_as_int(__int_as_float(r.y) * dl[n]);
            st2[cbase[n] + loc] = o;
        }
        __syncthreads();
        for (int j = t; j < len; j += 256) er[b0 + j] = st2[j];
    } else {
        for (int j = t; j < len; j += 256)
            atomicAdd(&cnt[(ert[b0 + j].x >> 20) & 63], 1u);
        __syncthreads();
        if (t < NPB) {
            unsigned c = cnt[t];
            dcount[t] = c;
            dl[t] = c ? 1.0f / sqrtf((float)c) : 0.0f;
        }
        __syncthreads();
        if (t == 0) {
            unsigned run = 0;
            for (int i = 0; i < NPB; ++i) { cbase[i] = run; run += cnt[i]; cnt[i] = 0; }
        }
        __syncthreads();
        for (int j = t; j < len; j += 256) {
            int2 r = ert[b0 + j];
            int n = (r.x >> 20) & 63;
            unsigned loc = atomicAdd(&cnt[n], 1u);
            int2 o;
            o.x = (int)((((unsigned)r.x & FMASK) << 7) | (((unsigned)n & 15u) << 1) |
                        ((loc == dcount[n] - 1) ? 1u : 0u));
            o.y = __float_as_int(__int_as_float(r.y) * dl[n]);
            er[b0 + (int)cbase[n] + (int)loc] = o;
        }
        __syncthreads();
    }
    int nbase = fb * NPB;
    if (t < NPB && nbase + t < N) {
        rowptr[nbase + t] = b0 + (int)cbase[t];
        dis[nbase + t] = dl[t];
    }
    if (fb == NFB - 1 && t == 0) rowptr[N] = b1;
}

// weight fragment table: wf[layer][mat][nt][ks][lane] = 8 f16 (16B), L1-resident in k_flayer
__global__ void k_wprep(const float* __restrict__ W1, const float* __restrict__ W2,
                        int Lnum, f16x8* __restrict__ wf) {
    int idx = blockIdx.x * blockDim.x + threadIdx.x;   // (layer*16 + frag)*64 + lane
    if (idx >= Lnum * 16 * 64) return;
    int lane = idx & 63;
    int fr = (idx >> 6) & 15;
    int l = idx >> 10;
    int mat = fr >> 3, nt = (fr >> 1) & 3, ks = fr & 1;
    int j = nt * 16 + (lane & 15);
    int kb = ((lane >> 4) << 3) + ks * 32;
    const float* src = (mat ? W2 : W1) + (size_t)l * D * D + j * D + kb;
    f16x8 v;
#pragma unroll
    for (int q = 0; q < 8; ++q) v[q] = (_Float16)src[q];
    wf[idx] = v;
}

// fused setup streaming pass: er.y *= dis[frm]  AND  emb -> x(fp16), out0, out1-cols0..63
__global__ void k_prep(int2* __restrict__ er, const float* __restrict__ dis, int E,
                       const float* __restrict__ emb, __half* __restrict__ x,
                       float* __restrict__ out, int N) {
    int total = E + N * 16;
    int st = gridDim.x * blockDim.x;
    const float4* e4 = (const float4*)emb;
    float4* o4 = (float4*)out;
    __half2* xh = (__half2*)x;
    for (int i = blockIdx.x * blockDim.x + threadIdx.x; i < total; i += st) {
        if (i < E) {
            int2 r = er[i];
            er[i].y = __float_as_int(__int_as_float(r.y) * dis[(unsigned)r.x >> 7]);
        } else {
            int j = i - E;
            float4 v = e4[j];
            o4[j] = v;
            int n = j >> 4, c = j & 15;
            o4[(size_t)N * 16 + (size_t)n * 32 + c] = v;
            xh[2 * j]     = __floats2half2_rn(v.x, v.y);
            xh[2 * j + 1] = __floats2half2_rn(v.z, v.w);
        }
    }
}

// s[n] = sum of final norms over n's edges (layer-invariant; runs after k_prep)
__global__ void k_sums(const int2* __restrict__ er, const int* __restrict__ rowptr,
                       int N, float* __restrict__ s) {
    int n = blockIdx.x * blockDim.x + threadIdx.x;
    if (n >= N) return;
    int e0 = rowptr[n], e1 = rowptr[n + 1];
    float sv = 0.0f;
    for (int e = e0; e < e1; ++e) sv += __int_as_float(er[e].y);
    s[n] = sv;
}

// flush: combine even/odd halves, lo lanes write float2 to LDS row tl, reset.
__device__ __forceinline__ void flushf(float* __restrict__ gtw, int tl, int c32, bool hib,
                                       float& g0, float& g1) {
    float s0 = g0 + __shfl_xor(g0, 32);
    float s1 = g1 + __shfl_xor(g1, 32);
    if (!hib) {
        float2* p = (float2*)&gtw[tl * GTP + (c32 << 1)];
        float2 v; v.x = s0; v.y = s1;
        *p = v;
    }
    g0 = 0.0f; g1 = 0.0f;
}

// fused layer, 1-WAVE BLOCKS (fine-grained scheduling / max occupancy):
// each block = one wave = one 16-node tile. Records carry pre-baked byte
// offset + tile-row + flag: addr = (rx & ~0x7F) + coff, row = (rx>>1)&15,
// flag = rx&1. half2 dual-edge packing (1 VMEM/edge). MFMA epilogue from LDS.
__global__ __launch_bounds__(64, 8) void k_flayer(
        const int* __restrict__ rowptr, const int2* __restrict__ er,
        const __half* __restrict__ xin, const f16x8* __restrict__ wfg,
        const float* __restrict__ s,
        const float* __restrict__ b1, const float* __restrict__ b2,
        int N, float* __restrict__ outf, __half* __restrict__ outh, int ostride) {
    __shared__ __align__(16) float gt[16 * GTP];        // 4.4 KB, one tile
    int lane = threadIdx.x;
    int tb = blockIdx.x * 16;
    float* gtw = gt;
#pragma unroll
    for (int p = 0; p < 16; ++p) gtw[p * GTP + lane] = 0.0f;
    int e = rowptr[tb], eend = rowptr[tb + 16];
    const char* xbase = (const char*)xin;
    int c32 = lane & 31;
    bool hib = lane >= 32;
    unsigned coff = (unsigned)c32 << 2;
    if (e < eend) {
        float g0 = 0.0f, g1 = 0.0f;
        // leading odd edge -> even alignment for int4 record loads
        if (e & 1) {
            int2 r = er[e];
            unsigned rx = (unsigned)r.x;
            float nv = hib ? 0.0f : __int_as_float(r.y);
            __half2 hv = *(const __half2*)(xbase + (rx & ~0x7Fu) + coff);
            g0 = fmaf(nv, __low2float(hv), g0);
            g1 = fmaf(nv, __high2float(hv), g1);
            if (rx & 1u) flushf(gtw, (rx >> 1) & 15, c32, hib, g0, g1);
            ++e;
        }
        while (e + 16 <= eend) {
            int4 rc[8];
#pragma unroll
            for (int k = 0; k < 8; ++k) rc[k] = *(const int4*)&er[e + 2 * k];
            __half2 hv[8];
            float nv[8];
#pragma unroll
            for (int k = 0; k < 8; ++k) {
                unsigned rx = (unsigned)(hib ? rc[k].z : rc[k].x);
                nv[k] = __int_as_float(hib ? rc[k].w : rc[k].y);
                hv[k] = *(const __half2*)(xbase + (rx & ~0x7Fu) + coff);
            }
#pragma unroll
            for (int k = 0; k < 8; ++k) {
                unsigned rxl = (unsigned)rc[k].x, rxh = (unsigned)rc[k].z;
                float c0 = nv[k] * __low2float(hv[k]);
                float c1 = nv[k] * __high2float(hv[k]);
                if (!((rxl | rxh) & 1u)) {             // fast path, wave-uniform
                    g0 += c0; g1 += c1;
                } else if (rxl & 1u) {
                    if (!hib) { g0 += c0; g1 += c1; }
                    flushf(gtw, (rxl >> 1) & 15, c32, hib, g0, g1);
                    if (hib) { g0 += c0; g1 += c1; }
                    if (rxh & 1u) flushf(gtw, (rxh >> 1) & 15, c32, hib, g0, g1);
                } else {                               // only hi flagged
                    g0 += c0; g1 += c1;
                    flushf(gtw, (rxh >> 1) & 15, c32, hib, g0, g1);
                }
            }
            e += 16;
        }
        // tail pairs
        while (e + 2 <= eend) {
            int4 rc = *(const int4*)&er[e];
            unsigned rxl = (unsigned)rc.x, rxh = (unsigned)rc.z;
            unsigned rx = hib ? rxh : rxl;
            float nv = __int_as_float(hib ? rc.w : rc.y);
            __half2 hvv = *(const __half2*)(xbase + (rx & ~0x7Fu) + coff);
            float c0 = nv * __low2float(hvv);
            float c1 = nv * __high2float(hvv);
            if (!((rxl | rxh) & 1u)) {
                g0 += c0; g1 += c1;
            } else if (rxl & 1u) {
                if (!hib) { g0 += c0; g1 += c1; }
                flushf(gtw, (rxl >> 1) & 15, c32, hib, g0, g1);
                if (hib) { g0 += c0; g1 += c1; }
                if (rxh & 1u) flushf(gtw, (rxh >> 1) & 15, c32, hib, g0, g1);
            } else {
                g0 += c0; g1 += c1;
                flushf(gtw, (rxh >> 1) & 15, c32, hib, g0, g1);
            }
            e += 2;
        }
        // final single edge
        if (e < eend) {
            int2 r = er[e];
            unsigned rx = (unsigned)r.x;
            float nv = hib ? 0.0f : __int_as_float(r.y);
            __half2 hvv = *(const __half2*)(xbase + (rx & ~0x7Fu) + coff);
            g0 = fmaf(nv, __low2float(hvv), g0);
            g1 = fmaf(nv, __high2float(hvv), g1);
            if (rx & 1u) flushf(gtw, (rx >> 1) & 15, c32, hib, g0, g1);
        }
    }
    // ---- MFMA update (wave-private LDS; compiler orders via lgkmcnt) ----
    int L = lane & 15, H = lane >> 4;
    f16x8 a1[2], a2[2];
#pragma unroll
    for (int ks = 0; ks < 2; ++ks) {
        const float* gp = &gtw[L * GTP + (H << 3) + ks * 32];
        f32x4 g0v = *(const f32x4*)gp;
        f32x4 g1v = *(const f32x4*)(gp + 4);
        f16x8 xv = *(const f16x8*)(xin + (((size_t)(tb + L)) << 6) + (H << 3) + ks * 32);
        f16x8 h1v, h2v;
#pragma unroll
        for (int q = 0; q < 4; ++q) {
            float gq = g0v[q], xq = (float)xv[q];
            h1v[q] = (_Float16)(gq + xq);
            h2v[q] = (_Float16)(gq * xq);
        }
#pragma unroll
        for (int q = 0; q < 4; ++q) {
            float gq = g1v[q], xq = (float)xv[4 + q];
            h1v[4 + q] = (_Float16)(gq + xq);
            h2v[4 + q] = (_Float16)(gq * xq);
        }
        a1[ks] = h1v; a2[ks] = h2v;
    }
    float sr[4];
#pragma unroll
    for (int r = 0; r < 4; ++r) sr[r] = s[tb + (H << 2) + r];
#pragma unroll
    for (int nt = 0; nt < 4; ++nt) {
        f16x8 w0 = wfg[(nt * 2 + 0) * 64 + lane];
        f16x8 w1 = wfg[(nt * 2 + 1) * 64 + lane];
        f16x8 w2 = wfg[(8 + nt * 2 + 0) * 64 + lane];
        f16x8 w3 = wfg[(8 + nt * 2 + 1) * 64 + lane];
        float bb1 = b1[nt * 16 + L], bb2 = b2[nt * 16 + L];
        f32x4 acc;
#pragma unroll
        for (int r = 0; r < 4; ++r) acc[r] = (sr[r] + 1.0f) * bb1 + sr[r] * bb2;
        acc = __builtin_amdgcn_mfma_f32_16x16x32_f16(a1[0], w0, acc, 0, 0, 0);
        acc = __builtin_amdgcn_mfma_f32_16x16x32_f16(a1[1], w1, acc, 0, 0, 0);
        acc = __builtin_amdgcn_mfma_f32_16x16x32_f16(a2[0], w2, acc, 0, 0, 0);
        acc = __builtin_amdgcn_mfma_f32_16x16x32_f16(a2[1], w3, acc, 0, 0, 0);
#pragma unroll
        for (int r = 0; r < 4; ++r) {
            float v = acc[r];
            v = v > 0.0f ? v : 0.01f * v;
            int row = tb + (H << 2) + r;
            if (outf) outf[(size_t)row * ostride + nt * 16 + L] = v;
            else      outh[((size_t)row << 6) + nt * 16 + L] = __float2half(v);
        }
        __builtin_amdgcn_sched_barrier(0);
    }
}

extern "C" void kernel_launch(void* const* d_in, const int* in_sizes, int n_in,
                              void* d_out, int out_size, void* d_ws, size_t ws_size,
                              hipStream_t stream) {
    const int* eidx = (const int*)d_in[0];
    const float* w = (const float*)d_in[1];
    const float* emb = (const float*)d_in[2];
    const float* W1 = (const float*)d_in[3];
    const float* b1 = (const float*)d_in[4];
    const float* W2 = (const float*)d_in[5];
    const float* b2 = (const float*)d_in[6];

    int E = in_sizes[1];
    int N = in_sizes[2] / D;
    int L = in_sizes[3] / (D * D);
    const int* frm = eidx;
    const int* to = eidx + E;
    int NFB = (N + NPB - 1) / NPB;

    char* ws = (char*)d_ws;
    size_t off = 0;
    __half* x0 = (__half*)(ws + off);      off += align256((size_t)N * D * 2);
    __half* x1 = (__half*)(ws + off);      off += align256((size_t)N * D * 2);
    int2* er = (int2*)(ws + off);          off += align256((size_t)E * 8);
    int2* ert = (int2*)(ws + off);         off += align256((size_t)E * 8);
    int* rowptr = (int*)(ws + off);        off += align256((size_t)(N + 1) * 4);
    float* dis = (float*)(ws + off);       off += align256((size_t)N * 4);
    float* s = (float*)(ws + off);         off += align256((size_t)N * 4);
    unsigned* bcnt = (unsigned*)(ws + off);off += align256((size_t)MAXFB * 4);
    int* fine_base = (int*)(ws + off);     off += align256((size_t)(MAXFB + 1) * 4);
    int* gcur = (int*)(ws + off);          off += align256((size_t)MAXFB * 4);
    f16x8* wf = (f16x8*)(ws + off);        off += align256((size_t)L * 16 * 64 * 16);

    float* out = (float*)d_out;

    hipMemsetAsync(bcnt, 0, (size_t)MAXFB * 4, stream);
    k_wprep<<<(L * 16 * 64 + 255) / 256, 256, 0, stream>>>(W1, W2, L, wf);
    k_hist<<<(E + CHUNK_H - 1) / CHUNK_H, 1024, 0, stream>>>(to, E, NFB, bcnt);
    k_scanb<<<1, 1024, 0, stream>>>(bcnt, NFB, fine_base, gcur);
    k_cfill<<<(E + CHUNK - 1) / CHUNK, 1024, 0, stream>>>(frm, to, w, E, NFB, gcur, ert);
    k_bsort<<<NFB, 256, 0, stream>>>(ert, fine_base, N, NFB, er, rowptr, dis);
    k_prep<<<2048, 256, 0, stream>>>(er, dis, E, emb, x0, out, N);
    k_sums<<<(N + 255) / 256, 256, 0, stream>>>(er, rowptr, N, s);

    __half* xin = x0;
    __half* xalt = x1;
    int ntiles = (N + 15) / 16;   // one 1-wave block per 16-node tile
    for (int l = 0; l < L; ++l) {
        float* outf = nullptr;
        __half* outh = xalt;
        int ostride = D;
        if (l == L - 1) {
            outf = out + (size_t)N * D + D;  // output 1, cols 64..127
            outh = nullptr;
            ostride = 2 * D;
        }
        k_flayer<<<ntiles, 64, 0, stream>>>(rowptr, er, xin,
                                            wf + (size_t)l * 16 * 64, s,
                                            b1 + (size_t)l * D, b2 + (size_t)l * D,
                                            N, outf, outh, ostride);
        __half* t = xin; xin = xalt; xalt = t;
    }
}